// Round 1
// baseline (898.311 us; speedup 1.0000x reference)
//
#include <hip/hip_runtime.h>
#include <math.h>

#define NTHREADS 256

static __device__ __forceinline__ float siluf(float x) {
    return x / (1.f + __expf(-x));
}
static __device__ __forceinline__ float softplusf(float x) {
    return fmaxf(x, 0.f) + log1pf(__expf(-fabsf(x)));
}

// ---------------------------------------------------------------------------
// Gather the im2col matrix for the embedding conv (edge-padded, k=3).
// Aemb[row, c*3+j] = x_enc[b, clamp(t+j-2,0,1023), c], row = b*1024+t.
__global__ __launch_bounds__(NTHREADS) void gather_embed(
    const float* __restrict__ xe, float* __restrict__ Aemb)
{
    int idx = blockIdx.x * NTHREADS + threadIdx.x; // 4096*96
    int row = idx / 96, k = idx % 96;
    int c = k / 3, j = k % 3;
    int b = row >> 10, t = row & 1023;
    int tc = min(max(t + j - 2, 0), 1023);
    Aemb[idx] = xe[(b * 1024 + tc) * 32 + c];
}

// ---------------------------------------------------------------------------
// Generic fp32 GEMM: C[M,N] = A[M,K] @ B[N,K]^T (+bias)(+softplus)
// BM=BN=64, BK=16, 256 threads, 4x4 accum per thread.
__global__ __launch_bounds__(NTHREADS) void gemm_nt(
    const float* __restrict__ A, int lda,
    const float* __restrict__ B, int ldb,
    const float* __restrict__ bias,
    float* __restrict__ C, int ldc,
    int K, int act)
{
    __shared__ float As[16][68];
    __shared__ float Bs[16][68];
    const int tid = threadIdx.x;
    const int tx = tid & 15, ty = tid >> 4;
    const int m0 = blockIdx.x * 64, n0 = blockIdx.y * 64;
    const int lr = tid >> 2;          // 0..63 tile row
    const int lc = (tid & 3) << 2;    // 0,4,8,12 tile k-col
    float acc[4][4] = {{0.f}};
    const float* Ap = A + (m0 + lr) * lda + lc;
    const float* Bp = B + (n0 + lr) * ldb + lc;
    for (int k0 = 0; k0 < K; k0 += 16) {
        float4 av = *(const float4*)(Ap + k0);
        float4 bv = *(const float4*)(Bp + k0);
        __syncthreads();
        As[lc + 0][lr] = av.x; As[lc + 1][lr] = av.y;
        As[lc + 2][lr] = av.z; As[lc + 3][lr] = av.w;
        Bs[lc + 0][lr] = bv.x; Bs[lc + 1][lr] = bv.y;
        Bs[lc + 2][lr] = bv.z; Bs[lc + 3][lr] = bv.w;
        __syncthreads();
#pragma unroll
        for (int kk = 0; kk < 16; ++kk) {
            float4 a = *(const float4*)&As[kk][ty << 2];
            float4 b = *(const float4*)&Bs[kk][tx << 2];
            acc[0][0] += a.x * b.x; acc[0][1] += a.x * b.y;
            acc[0][2] += a.x * b.z; acc[0][3] += a.x * b.w;
            acc[1][0] += a.y * b.x; acc[1][1] += a.y * b.y;
            acc[1][2] += a.y * b.z; acc[1][3] += a.y * b.w;
            acc[2][0] += a.z * b.x; acc[2][1] += a.z * b.y;
            acc[2][2] += a.z * b.z; acc[2][3] += a.z * b.w;
            acc[3][0] += a.w * b.x; acc[3][1] += a.w * b.y;
            acc[3][2] += a.w * b.z; acc[3][3] += a.w * b.w;
        }
    }
#pragma unroll
    for (int i = 0; i < 4; ++i) {
        int mrow = m0 + (ty << 2) + i;
#pragma unroll
        for (int j = 0; j < 4; ++j) {
            int ncol = n0 + (tx << 2) + j;
            float v = acc[i][j];
            if (bias) v += bias[ncol];
            if (act == 1) v = softplusf(v);
            C[mrow * ldc + ncol] = v;
        }
    }
}

// ---------------------------------------------------------------------------
// x += positional embedding (sinusoidal), x is (4096, 512), row%1024 = t.
__global__ __launch_bounds__(NTHREADS) void posemb_add(float* __restrict__ x)
{
    int idx = blockIdx.x * NTHREADS + threadIdx.x; // 4096*512
    int row = idx >> 9, d = idx & 511;
    int t = row & 1023;
    int i2 = d >> 1;
    float lf = logf(10000.f) * (1.f / 512.f);
    float freq = expf(-(float)(2 * i2) * lf);
    float ang = (float)t * freq;
    x[idx] += (d & 1) ? cosf(ang) : sinf(ang);
}

// ---------------------------------------------------------------------------
// Depthwise causal conv1d (D_CONV=4, zero left pad) + bias + SiLU.
// in: xi part of xz (stride 2048). out: xic (4096,1024).
__global__ __launch_bounds__(NTHREADS) void dwconv_silu(
    const float* __restrict__ xz, const float* __restrict__ w,
    const float* __restrict__ bias, float* __restrict__ out)
{
    int idx = blockIdx.x * NTHREADS + threadIdx.x; // 4096*1024
    int row = idx >> 10;      // b*1024 + l
    int d = idx & 1023;
    int b = row >> 10, l = row & 1023;
    float acc = bias[d];
#pragma unroll
    for (int j = 0; j < 4; ++j) {
        int ls = l - 3 + j;
        if (ls >= 0) acc += xz[(b * 1024 + ls) * 2048 + d] * w[d * 4 + j];
    }
    out[idx] = siluf(acc);
}

// ---------------------------------------------------------------------------
// Selective scan, fused with +xi*D and *silu(z) gating.
// One thread per (b, d) channel; 16 blocks of 256.
__global__ __launch_bounds__(NTHREADS) void scan_fused(
    const float* __restrict__ delta, const float* __restrict__ xic,
    const float* __restrict__ dbc, const float* __restrict__ xz,
    const float* __restrict__ A_log, const float* __restrict__ Dp,
    float* __restrict__ yz)
{
    int b = blockIdx.x >> 2;
    int d = ((blockIdx.x & 3) << 8) + threadIdx.x;
    float Ac[16];
#pragma unroll
    for (int s = 0; s < 16; s += 4) {
        float4 v = *(const float4*)(A_log + d * 16 + s);
        Ac[s + 0] = -expf(v.x); Ac[s + 1] = -expf(v.y);
        Ac[s + 2] = -expf(v.z); Ac[s + 3] = -expf(v.w);
    }
    float dp = Dp[d];
    float h[16];
#pragma unroll
    for (int s = 0; s < 16; ++s) h[s] = 0.f;
    int base = b * 1024;
    for (int l = 0; l < 1024; ++l) {
        int row = base + l;
        float dl = delta[row * 1024 + d];
        float xv = xic[row * 1024 + d];
        float zv = xz[row * 2048 + 1024 + d];
        const float* bc = dbc + row * 64;
        float Bl[16], Cl[16];
#pragma unroll
        for (int s = 0; s < 16; s += 4) {
            float4 bV = *(const float4*)(bc + 32 + s);
            float4 cV = *(const float4*)(bc + 48 + s);
            Bl[s + 0] = bV.x; Bl[s + 1] = bV.y; Bl[s + 2] = bV.z; Bl[s + 3] = bV.w;
            Cl[s + 0] = cV.x; Cl[s + 1] = cV.y; Cl[s + 2] = cV.z; Cl[s + 3] = cV.w;
        }
        float dxi = dl * xv;
        float y = 0.f;
#pragma unroll
        for (int s = 0; s < 16; ++s) {
            float dA = __expf(dl * Ac[s]);
            h[s] = dA * h[s] + dxi * Bl[s];
            y += h[s] * Cl[s];
        }
        y += xv * dp;
        yz[row * 1024 + d] = y * siluf(zv);
    }
}

// ---------------------------------------------------------------------------
// LayerNorm over 512, in place. One wave per row, 4 rows per block.
__global__ __launch_bounds__(NTHREADS) void layernorm_ip(
    float* __restrict__ mo, const float* __restrict__ w, const float* __restrict__ bvec)
{
    int wv = threadIdx.x >> 6, lane = threadIdx.x & 63;
    int row = (blockIdx.x << 2) + wv;
    float* p = mo + row * 512;
    float4 v0 = ((const float4*)p)[lane];
    float4 v1 = ((const float4*)p)[lane + 64];
    float s = v0.x + v0.y + v0.z + v0.w + v1.x + v1.y + v1.z + v1.w;
    float q = v0.x * v0.x + v0.y * v0.y + v0.z * v0.z + v0.w * v0.w
            + v1.x * v1.x + v1.y * v1.y + v1.z * v1.z + v1.w * v1.w;
#pragma unroll
    for (int off = 32; off; off >>= 1) {
        s += __shfl_xor(s, off);
        q += __shfl_xor(q, off);
    }
    float mean = s * (1.f / 512.f);
    float var = q * (1.f / 512.f) - mean * mean;
    float rstd = rsqrtf(var + 1e-5f);
    float4 w0 = ((const float4*)w)[lane], w1 = ((const float4*)w)[lane + 64];
    float4 b0 = ((const float4*)bvec)[lane], b1 = ((const float4*)bvec)[lane + 64];
    v0.x = (v0.x - mean) * rstd * w0.x + b0.x;
    v0.y = (v0.y - mean) * rstd * w0.y + b0.y;
    v0.z = (v0.z - mean) * rstd * w0.z + b0.z;
    v0.w = (v0.w - mean) * rstd * w0.w + b0.w;
    v1.x = (v1.x - mean) * rstd * w1.x + b1.x;
    v1.y = (v1.y - mean) * rstd * w1.y + b1.y;
    v1.z = (v1.z - mean) * rstd * w1.z + b1.z;
    v1.w = (v1.w - mean) * rstd * w1.w + b1.w;
    ((float4*)p)[lane] = v0;
    ((float4*)p)[lane + 64] = v1;
}

// ---------------------------------------------------------------------------
// logits (10) + importance scalar per row. One wave per row.
__global__ __launch_bounds__(NTHREADS) void head_k(
    const float* __restrict__ mo, const float* __restrict__ Wc,
    const float* __restrict__ ifw, const float* __restrict__ ifb,
    float* __restrict__ logits, float* __restrict__ imp)
{
    int wv = threadIdx.x >> 6, lane = threadIdx.x & 63;
    int row = (blockIdx.x << 2) + wv;
    const float* p = mo + row * 512 + lane * 8;
    float4 x0 = *(const float4*)p;
    float4 x1 = *(const float4*)(p + 4);
    float part[11];
#pragma unroll
    for (int c = 0; c < 10; ++c) {
        const float* wr = Wc + c * 512 + lane * 8;
        float4 w0 = *(const float4*)wr, w1 = *(const float4*)(wr + 4);
        part[c] = x0.x * w0.x + x0.y * w0.y + x0.z * w0.z + x0.w * w0.w
                + x1.x * w1.x + x1.y * w1.y + x1.z * w1.z + x1.w * w1.w;
    }
    {
        const float* wr = ifw + lane * 8;
        float4 w0 = *(const float4*)wr, w1 = *(const float4*)(wr + 4);
        part[10] = x0.x * w0.x + x0.y * w0.y + x0.z * w0.z + x0.w * w0.w
                 + x1.x * w1.x + x1.y * w1.y + x1.z * w1.z + x1.w * w1.w;
    }
#pragma unroll
    for (int i = 0; i < 11; ++i)
#pragma unroll
        for (int off = 32; off; off >>= 1) part[i] += __shfl_xor(part[i], off);
    if (lane == 0) {
#pragma unroll
        for (int c = 0; c < 10; ++c) logits[row * 10 + c] = part[c];
        imp[row] = part[10] + ifb[0];
    }
}

// ---------------------------------------------------------------------------
// Per-batch softmax pooling: out[b,c] = sum_l logits*mark^2*e / sum_l e*mark.
__global__ __launch_bounds__(NTHREADS) void final_k(
    const float* __restrict__ logits, const float* __restrict__ imp,
    const float* __restrict__ mark, float* __restrict__ out)
{
    __shared__ float sred[4];
    int b = blockIdx.x, tid = threadIdx.x;
    int wv = tid >> 6, lane = tid & 63;
    float m = -1e30f;
    for (int l = tid; l < 1024; l += NTHREADS) m = fmaxf(m, imp[b * 1024 + l]);
#pragma unroll
    for (int off = 32; off; off >>= 1) m = fmaxf(m, __shfl_xor(m, off));
    if (lane == 0) sred[wv] = m;
    __syncthreads();
    m = fmaxf(fmaxf(sred[0], sred[1]), fmaxf(sred[2], sred[3]));
    __syncthreads();
    float den = 0.f, num[10];
#pragma unroll
    for (int c = 0; c < 10; ++c) num[c] = 0.f;
    for (int l = tid; l < 1024; l += NTHREADS) {
        float e = __expf(imp[b * 1024 + l] - m);
        float mk = mark[b * 1024 + l];
        den += e * mk;
        float w2 = e * mk * mk;
        const float* lg = logits + (b * 1024 + l) * 10;
#pragma unroll
        for (int c = 0; c < 10; ++c) num[c] += lg[c] * w2;
    }
#pragma unroll
    for (int off = 32; off; off >>= 1) den += __shfl_xor(den, off);
    if (lane == 0) sred[wv] = den;
    __syncthreads();
    den = sred[0] + sred[1] + sred[2] + sred[3];
    __syncthreads();
#pragma unroll
    for (int c = 0; c < 10; ++c) {
        float v = num[c];
#pragma unroll
        for (int off = 32; off; off >>= 1) v += __shfl_xor(v, off);
        if (lane == 0) sred[wv] = v;
        __syncthreads();
        v = sred[0] + sred[1] + sred[2] + sred[3];
        __syncthreads();
        num[c] = v;
    }
    if (tid == 0) {
        float inv = 1.f / den;
#pragma unroll
        for (int c = 0; c < 10; ++c) out[b * 10 + c] = num[c] * inv;
    }
}

// ---------------------------------------------------------------------------
extern "C" void kernel_launch(void* const* d_in, const int* in_sizes, int n_in,
                              void* d_out, int out_size, void* d_ws, size_t ws_size,
                              hipStream_t stream) {
    (void)in_sizes; (void)n_in; (void)out_size; (void)ws_size;
    const float* x_enc      = (const float*)d_in[0];
    const float* mark       = (const float*)d_in[1];
    const float* conv_w     = (const float*)d_in[4];
    const float* in_proj_w  = (const float*)d_in[5];
    const float* conv1d_w   = (const float*)d_in[6];
    const float* conv1d_b   = (const float*)d_in[7];
    const float* x_proj_w   = (const float*)d_in[8];
    const float* dt_proj_w  = (const float*)d_in[9];
    const float* dt_proj_b  = (const float*)d_in[10];
    const float* A_log      = (const float*)d_in[11];
    const float* Dp         = (const float*)d_in[12];
    const float* out_proj_w = (const float*)d_in[13];
    const float* ln_w       = (const float*)d_in[14];
    const float* ln_b       = (const float*)d_in[15];
    const float* out_layer_w= (const float*)d_in[16];
    const float* if_w       = (const float*)d_in[17];
    const float* if_b       = (const float*)d_in[18];
    float* out = (float*)d_out;

    char* ws = (char*)d_ws;
    float* Aemb  = (float*)ws;                       // 4096*96   (reused: logits+imp)
    float* xbuf  = (float*)(ws + 1572864);           // 4096*512  (reused: mo)
    float* xz    = (float*)(ws + 1572864 + 8388608);           // 4096*2048
    float* xic   = (float*)(ws + 1572864 + 8388608 + 33554432);  // 4096*1024
    float* dbc   = (float*)(ws + 1572864 + 8388608 + 33554432 + 16777216); // 4096*64
    float* delta = (float*)(ws + 1572864 + 8388608 + 33554432 + 16777216 + 1048576); // 4096*1024
    float* yzb   = (float*)(ws + 1572864 + 8388608 + 33554432 + 16777216 + 1048576 + 16777216); // 4096*1024
    float* mo     = xbuf;   // xbuf dead after in_proj
    float* logits = Aemb;   // Aemb dead after embed GEMM
    float* impb   = Aemb + 4096 * 10;

    // 1. im2col gather for embedding conv
    gather_embed<<<1536, NTHREADS, 0, stream>>>(x_enc, Aemb);
    // 2. embed GEMM: (4096x96) @ (512x96)^T -> x
    gemm_nt<<<dim3(64, 8), NTHREADS, 0, stream>>>(Aemb, 96, conv_w, 96, nullptr, xbuf, 512, 96, 0);
    // 3. += positional embedding
    posemb_add<<<8192, NTHREADS, 0, stream>>>(xbuf);
    // 4. in_proj: (4096x512) @ (2048x512)^T -> xz
    gemm_nt<<<dim3(64, 32), NTHREADS, 0, stream>>>(xbuf, 512, in_proj_w, 512, nullptr, xz, 2048, 512, 0);
    // 5. depthwise conv + SiLU -> xic
    dwconv_silu<<<16384, NTHREADS, 0, stream>>>(xz, conv1d_w, conv1d_b, xic);
    // 6. x_proj: (4096x1024) @ (64x1024)^T -> dbc
    gemm_nt<<<dim3(64, 1), NTHREADS, 0, stream>>>(xic, 1024, x_proj_w, 1024, nullptr, dbc, 64, 1024, 0);
    // 7. dt_proj + bias + softplus: (4096x32 of dbc) @ (1024x32)^T -> delta
    gemm_nt<<<dim3(64, 16), NTHREADS, 0, stream>>>(dbc, 64, dt_proj_w, 32, dt_proj_b, delta, 1024, 32, 1);
    // 8. selective scan fused with gating -> yz
    scan_fused<<<16, NTHREADS, 0, stream>>>(delta, xic, dbc, xz, A_log, Dp, yzb);
    // 9. out_proj: (4096x1024) @ (512x1024)^T -> mo
    gemm_nt<<<dim3(64, 8), NTHREADS, 0, stream>>>(yzb, 1024, out_proj_w, 1024, nullptr, mo, 512, 1024, 0);
    // 10. LayerNorm in place
    layernorm_ip<<<1024, NTHREADS, 0, stream>>>(mo, ln_w, ln_b);
    // 11. logits + importance per row
    head_k<<<1024, NTHREADS, 0, stream>>>(mo, out_layer_w, if_w, if_b, logits, impb);
    // 12. softmax pooling -> out (4,10)
    final_k<<<4, NTHREADS, 0, stream>>>(logits, impb, mark, out);
}

// Round 2
// 413.500 us; speedup vs baseline: 2.1725x; 2.1725x over previous
//
#include <hip/hip_runtime.h>
#include <math.h>

#define NTHREADS 256
#define NC 32   // scan chunks
#define CL 32   // chunk length (NC*CL = 1024)

static __device__ __forceinline__ float siluf(float x) {
    return x / (1.f + __expf(-x));
}
static __device__ __forceinline__ float softplusf(float x) {
    return fmaxf(x, 0.f) + log1pf(__expf(-fabsf(x)));
}

// ---------------------------------------------------------------------------
// Gather the im2col matrix for the embedding conv (edge-padded, k=3).
__global__ __launch_bounds__(NTHREADS) void gather_embed(
    const float* __restrict__ xe, float* __restrict__ Aemb)
{
    int idx = blockIdx.x * NTHREADS + threadIdx.x; // 4096*96
    int row = idx / 96, k = idx % 96;
    int c = k / 3, j = k % 3;
    int b = row >> 10, t = row & 1023;
    int tc = min(max(t + j - 2, 0), 1023);
    Aemb[idx] = xe[(b * 1024 + tc) * 32 + c];
}

// ---------------------------------------------------------------------------
// Generic fp32 GEMM: C[M,N] = A[M,K] @ B[N,K]^T (+bias)(+softplus)
__global__ __launch_bounds__(NTHREADS) void gemm_nt(
    const float* __restrict__ A, int lda,
    const float* __restrict__ B, int ldb,
    const float* __restrict__ bias,
    float* __restrict__ C, int ldc,
    int K, int act)
{
    __shared__ float As[16][68];
    __shared__ float Bs[16][68];
    const int tid = threadIdx.x;
    const int tx = tid & 15, ty = tid >> 4;
    const int m0 = blockIdx.x * 64, n0 = blockIdx.y * 64;
    const int lr = tid >> 2;
    const int lc = (tid & 3) << 2;
    float acc[4][4] = {{0.f}};
    const float* Ap = A + (m0 + lr) * lda + lc;
    const float* Bp = B + (n0 + lr) * ldb + lc;
    for (int k0 = 0; k0 < K; k0 += 16) {
        float4 av = *(const float4*)(Ap + k0);
        float4 bv = *(const float4*)(Bp + k0);
        __syncthreads();
        As[lc + 0][lr] = av.x; As[lc + 1][lr] = av.y;
        As[lc + 2][lr] = av.z; As[lc + 3][lr] = av.w;
        Bs[lc + 0][lr] = bv.x; Bs[lc + 1][lr] = bv.y;
        Bs[lc + 2][lr] = bv.z; Bs[lc + 3][lr] = bv.w;
        __syncthreads();
#pragma unroll
        for (int kk = 0; kk < 16; ++kk) {
            float4 a = *(const float4*)&As[kk][ty << 2];
            float4 b = *(const float4*)&Bs[kk][tx << 2];
            acc[0][0] += a.x * b.x; acc[0][1] += a.x * b.y;
            acc[0][2] += a.x * b.z; acc[0][3] += a.x * b.w;
            acc[1][0] += a.y * b.x; acc[1][1] += a.y * b.y;
            acc[1][2] += a.y * b.z; acc[1][3] += a.y * b.w;
            acc[2][0] += a.z * b.x; acc[2][1] += a.z * b.y;
            acc[2][2] += a.z * b.z; acc[2][3] += a.z * b.w;
            acc[3][0] += a.w * b.x; acc[3][1] += a.w * b.y;
            acc[3][2] += a.w * b.z; acc[3][3] += a.w * b.w;
        }
    }
#pragma unroll
    for (int i = 0; i < 4; ++i) {
        int mrow = m0 + (ty << 2) + i;
#pragma unroll
        for (int j = 0; j < 4; ++j) {
            int ncol = n0 + (tx << 2) + j;
            float v = acc[i][j];
            if (bias) v += bias[ncol];
            if (act == 1) v = softplusf(v);
            C[mrow * ldc + ncol] = v;
        }
    }
}

// ---------------------------------------------------------------------------
__global__ __launch_bounds__(NTHREADS) void posemb_add(float* __restrict__ x)
{
    int idx = blockIdx.x * NTHREADS + threadIdx.x; // 4096*512
    int row = idx >> 9, d = idx & 511;
    int t = row & 1023;
    int i2 = d >> 1;
    float lf = logf(10000.f) * (1.f / 512.f);
    float freq = expf(-(float)(2 * i2) * lf);
    float ang = (float)t * freq;
    x[idx] += (d & 1) ? cosf(ang) : sinf(ang);
}

// ---------------------------------------------------------------------------
__global__ __launch_bounds__(NTHREADS) void dwconv_silu(
    const float* __restrict__ xz, const float* __restrict__ w,
    const float* __restrict__ bias, float* __restrict__ out)
{
    int idx = blockIdx.x * NTHREADS + threadIdx.x; // 4096*1024
    int row = idx >> 10;
    int d = idx & 1023;
    int b = row >> 10, l = row & 1023;
    float acc = bias[d];
#pragma unroll
    for (int j = 0; j < 4; ++j) {
        int ls = l - 3 + j;
        if (ls >= 0) acc += xz[(b * 1024 + ls) * 2048 + d] * w[d * 4 + j];
    }
    out[idx] = siluf(acc);
}

// ---------------------------------------------------------------------------
// Chunked selective scan, pass 1: per (b,d,chunk) local scan from h=0.
// Emits P = cumprod(dA) over the chunk and S = local final state.
__global__ __launch_bounds__(NTHREADS) void scan_p1(
    const float* __restrict__ delta, const float* __restrict__ xic,
    const float* __restrict__ dbc, const float* __restrict__ A_log,
    float* __restrict__ Pbuf, float* __restrict__ Sbuf)
{
    int blk = blockIdx.x;              // ((b*NC + c)*4 + g)
    int g = blk & 3;
    int c = (blk >> 2) & (NC - 1);
    int b = blk >> 7;
    int d = (g << 8) + threadIdx.x;
    float Ac[16];
#pragma unroll
    for (int s = 0; s < 16; s += 4) {
        float4 v = *(const float4*)(A_log + d * 16 + s);
        Ac[s + 0] = -expf(v.x); Ac[s + 1] = -expf(v.y);
        Ac[s + 2] = -expf(v.z); Ac[s + 3] = -expf(v.w);
    }
    float a[16], h[16];
#pragma unroll
    for (int s = 0; s < 16; ++s) { a[s] = 1.f; h[s] = 0.f; }
    int base = b * 1024 + c * CL;
    for (int l = 0; l < CL; ++l) {
        int row = base + l;
        float dl = delta[row * 1024 + d];
        float xv = xic[row * 1024 + d];
        const float* bc = dbc + row * 64 + 32;
        float dxi = dl * xv;
#pragma unroll
        for (int s = 0; s < 16; s += 4) {
            float4 bV = *(const float4*)(bc + s);
            float dA0 = __expf(dl * Ac[s + 0]);
            float dA1 = __expf(dl * Ac[s + 1]);
            float dA2 = __expf(dl * Ac[s + 2]);
            float dA3 = __expf(dl * Ac[s + 3]);
            a[s + 0] *= dA0; h[s + 0] = dA0 * h[s + 0] + dxi * bV.x;
            a[s + 1] *= dA1; h[s + 1] = dA1 * h[s + 1] + dxi * bV.y;
            a[s + 2] *= dA2; h[s + 2] = dA2 * h[s + 2] + dxi * bV.z;
            a[s + 3] *= dA3; h[s + 3] = dA3 * h[s + 3] + dxi * bV.w;
        }
    }
    int off = ((b * NC + c) * 1024 + d) * 16;
#pragma unroll
    for (int s = 0; s < 16; s += 4) {
        *(float4*)(Pbuf + off + s) = make_float4(a[s], a[s + 1], a[s + 2], a[s + 3]);
        *(float4*)(Sbuf + off + s) = make_float4(h[s], h[s + 1], h[s + 2], h[s + 3]);
    }
}

// ---------------------------------------------------------------------------
// Carry combine across chunks: H_c = P_c*H_{c-1} + S_c.
// Writes each chunk's INCOMING state H_{c-1} over Pbuf (in place).
__global__ __launch_bounds__(NTHREADS) void scan_carry(
    float* __restrict__ Pbuf, const float* __restrict__ Sbuf)
{
    int b = blockIdx.x >> 2;
    int d = ((blockIdx.x & 3) << 8) + threadIdx.x;
    float H[16];
#pragma unroll
    for (int s = 0; s < 16; ++s) H[s] = 0.f;
    for (int c = 0; c < NC; ++c) {
        int off = ((b * NC + c) * 1024 + d) * 16;
        float P[16], S[16];
#pragma unroll
        for (int s = 0; s < 16; s += 4) {
            float4 pv = *(const float4*)(Pbuf + off + s);
            float4 sv = *(const float4*)(Sbuf + off + s);
            P[s] = pv.x; P[s + 1] = pv.y; P[s + 2] = pv.z; P[s + 3] = pv.w;
            S[s] = sv.x; S[s + 1] = sv.y; S[s + 2] = sv.z; S[s + 3] = sv.w;
        }
#pragma unroll
        for (int s = 0; s < 16; s += 4)
            *(float4*)(Pbuf + off + s) = make_float4(H[s], H[s + 1], H[s + 2], H[s + 3]);
#pragma unroll
        for (int s = 0; s < 16; ++s) H[s] = P[s] * H[s] + S[s];
    }
}

// ---------------------------------------------------------------------------
// Pass 2: re-run each chunk from its true incoming state; emit gated output.
__global__ __launch_bounds__(NTHREADS) void scan_p2(
    const float* __restrict__ delta, const float* __restrict__ xic,
    const float* __restrict__ dbc, const float* __restrict__ xz,
    const float* __restrict__ A_log, const float* __restrict__ Dp,
    const float* __restrict__ Hprev, float* __restrict__ yz)
{
    int blk = blockIdx.x;
    int g = blk & 3;
    int c = (blk >> 2) & (NC - 1);
    int b = blk >> 7;
    int d = (g << 8) + threadIdx.x;
    float Ac[16];
#pragma unroll
    for (int s = 0; s < 16; s += 4) {
        float4 v = *(const float4*)(A_log + d * 16 + s);
        Ac[s + 0] = -expf(v.x); Ac[s + 1] = -expf(v.y);
        Ac[s + 2] = -expf(v.z); Ac[s + 3] = -expf(v.w);
    }
    float dp = Dp[d];
    float h[16];
    int off = ((b * NC + c) * 1024 + d) * 16;
#pragma unroll
    for (int s = 0; s < 16; s += 4) {
        float4 hv = *(const float4*)(Hprev + off + s);
        h[s] = hv.x; h[s + 1] = hv.y; h[s + 2] = hv.z; h[s + 3] = hv.w;
    }
    int base = b * 1024 + c * CL;
    for (int l = 0; l < CL; ++l) {
        int row = base + l;
        float dl = delta[row * 1024 + d];
        float xv = xic[row * 1024 + d];
        float zv = xz[row * 2048 + 1024 + d];
        const float* bc = dbc + row * 64;
        float dxi = dl * xv;
        float y = 0.f;
#pragma unroll
        for (int s = 0; s < 16; s += 4) {
            float4 bV = *(const float4*)(bc + 32 + s);
            float4 cV = *(const float4*)(bc + 48 + s);
            float dA0 = __expf(dl * Ac[s + 0]);
            float dA1 = __expf(dl * Ac[s + 1]);
            float dA2 = __expf(dl * Ac[s + 2]);
            float dA3 = __expf(dl * Ac[s + 3]);
            h[s + 0] = dA0 * h[s + 0] + dxi * bV.x;
            h[s + 1] = dA1 * h[s + 1] + dxi * bV.y;
            h[s + 2] = dA2 * h[s + 2] + dxi * bV.z;
            h[s + 3] = dA3 * h[s + 3] + dxi * bV.w;
            y += h[s + 0] * cV.x + h[s + 1] * cV.y + h[s + 2] * cV.z + h[s + 3] * cV.w;
        }
        y += xv * dp;
        yz[row * 1024 + d] = y * siluf(zv);
    }
}

// ---------------------------------------------------------------------------
__global__ __launch_bounds__(NTHREADS) void layernorm_ip(
    float* __restrict__ mo, const float* __restrict__ w, const float* __restrict__ bvec)
{
    int wv = threadIdx.x >> 6, lane = threadIdx.x & 63;
    int row = (blockIdx.x << 2) + wv;
    float* p = mo + row * 512;
    float4 v0 = ((const float4*)p)[lane];
    float4 v1 = ((const float4*)p)[lane + 64];
    float s = v0.x + v0.y + v0.z + v0.w + v1.x + v1.y + v1.z + v1.w;
    float q = v0.x * v0.x + v0.y * v0.y + v0.z * v0.z + v0.w * v0.w
            + v1.x * v1.x + v1.y * v1.y + v1.z * v1.z + v1.w * v1.w;
#pragma unroll
    for (int off = 32; off; off >>= 1) {
        s += __shfl_xor(s, off);
        q += __shfl_xor(q, off);
    }
    float mean = s * (1.f / 512.f);
    float var = q * (1.f / 512.f) - mean * mean;
    float rstd = rsqrtf(var + 1e-5f);
    float4 w0 = ((const float4*)w)[lane], w1 = ((const float4*)w)[lane + 64];
    float4 b0 = ((const float4*)bvec)[lane], b1 = ((const float4*)bvec)[lane + 64];
    v0.x = (v0.x - mean) * rstd * w0.x + b0.x;
    v0.y = (v0.y - mean) * rstd * w0.y + b0.y;
    v0.z = (v0.z - mean) * rstd * w0.z + b0.z;
    v0.w = (v0.w - mean) * rstd * w0.w + b0.w;
    v1.x = (v1.x - mean) * rstd * w1.x + b1.x;
    v1.y = (v1.y - mean) * rstd * w1.y + b1.y;
    v1.z = (v1.z - mean) * rstd * w1.z + b1.z;
    v1.w = (v1.w - mean) * rstd * w1.w + b1.w;
    ((float4*)p)[lane] = v0;
    ((float4*)p)[lane + 64] = v1;
}

// ---------------------------------------------------------------------------
__global__ __launch_bounds__(NTHREADS) void head_k(
    const float* __restrict__ mo, const float* __restrict__ Wc,
    const float* __restrict__ ifw, const float* __restrict__ ifb,
    float* __restrict__ logits, float* __restrict__ imp)
{
    int wv = threadIdx.x >> 6, lane = threadIdx.x & 63;
    int row = (blockIdx.x << 2) + wv;
    const float* p = mo + row * 512 + lane * 8;
    float4 x0 = *(const float4*)p;
    float4 x1 = *(const float4*)(p + 4);
    float part[11];
#pragma unroll
    for (int c = 0; c < 10; ++c) {
        const float* wr = Wc + c * 512 + lane * 8;
        float4 w0 = *(const float4*)wr, w1 = *(const float4*)(wr + 4);
        part[c] = x0.x * w0.x + x0.y * w0.y + x0.z * w0.z + x0.w * w0.w
                + x1.x * w1.x + x1.y * w1.y + x1.z * w1.z + x1.w * w1.w;
    }
    {
        const float* wr = ifw + lane * 8;
        float4 w0 = *(const float4*)wr, w1 = *(const float4*)(wr + 4);
        part[10] = x0.x * w0.x + x0.y * w0.y + x0.z * w0.z + x0.w * w0.w
                 + x1.x * w1.x + x1.y * w1.y + x1.z * w1.z + x1.w * w1.w;
    }
#pragma unroll
    for (int i = 0; i < 11; ++i)
#pragma unroll
        for (int off = 32; off; off >>= 1) part[i] += __shfl_xor(part[i], off);
    if (lane == 0) {
#pragma unroll
        for (int c = 0; c < 10; ++c) logits[row * 10 + c] = part[c];
        imp[row] = part[10] + ifb[0];
    }
}

// ---------------------------------------------------------------------------
__global__ __launch_bounds__(NTHREADS) void final_k(
    const float* __restrict__ logits, const float* __restrict__ imp,
    const float* __restrict__ mark, float* __restrict__ out)
{
    __shared__ float sred[4];
    int b = blockIdx.x, tid = threadIdx.x;
    int wv = tid >> 6, lane = tid & 63;
    float m = -1e30f;
    for (int l = tid; l < 1024; l += NTHREADS) m = fmaxf(m, imp[b * 1024 + l]);
#pragma unroll
    for (int off = 32; off; off >>= 1) m = fmaxf(m, __shfl_xor(m, off));
    if (lane == 0) sred[wv] = m;
    __syncthreads();
    m = fmaxf(fmaxf(sred[0], sred[1]), fmaxf(sred[2], sred[3]));
    __syncthreads();
    float den = 0.f, num[10];
#pragma unroll
    for (int c = 0; c < 10; ++c) num[c] = 0.f;
    for (int l = tid; l < 1024; l += NTHREADS) {
        float e = __expf(imp[b * 1024 + l] - m);
        float mk = mark[b * 1024 + l];
        den += e * mk;
        float w2 = e * mk * mk;
        const float* lg = logits + (b * 1024 + l) * 10;
#pragma unroll
        for (int c = 0; c < 10; ++c) num[c] += lg[c] * w2;
    }
#pragma unroll
    for (int off = 32; off; off >>= 1) den += __shfl_xor(den, off);
    if (lane == 0) sred[wv] = den;
    __syncthreads();
    den = sred[0] + sred[1] + sred[2] + sred[3];
    __syncthreads();
#pragma unroll
    for (int c = 0; c < 10; ++c) {
        float v = num[c];
#pragma unroll
        for (int off = 32; off; off >>= 1) v += __shfl_xor(v, off);
        if (lane == 0) sred[wv] = v;
        __syncthreads();
        v = sred[0] + sred[1] + sred[2] + sred[3];
        __syncthreads();
        num[c] = v;
    }
    if (tid == 0) {
        float inv = 1.f / den;
#pragma unroll
        for (int c = 0; c < 10; ++c) out[b * 10 + c] = num[c] * inv;
    }
}

// ---------------------------------------------------------------------------
extern "C" void kernel_launch(void* const* d_in, const int* in_sizes, int n_in,
                              void* d_out, int out_size, void* d_ws, size_t ws_size,
                              hipStream_t stream) {
    (void)in_sizes; (void)n_in; (void)out_size; (void)ws_size;
    const float* x_enc      = (const float*)d_in[0];
    const float* mark       = (const float*)d_in[1];
    const float* conv_w     = (const float*)d_in[4];
    const float* in_proj_w  = (const float*)d_in[5];
    const float* conv1d_w   = (const float*)d_in[6];
    const float* conv1d_b   = (const float*)d_in[7];
    const float* x_proj_w   = (const float*)d_in[8];
    const float* dt_proj_w  = (const float*)d_in[9];
    const float* dt_proj_b  = (const float*)d_in[10];
    const float* A_log      = (const float*)d_in[11];
    const float* Dp         = (const float*)d_in[12];
    const float* out_proj_w = (const float*)d_in[13];
    const float* ln_w       = (const float*)d_in[14];
    const float* ln_b       = (const float*)d_in[15];
    const float* out_layer_w= (const float*)d_in[16];
    const float* if_w       = (const float*)d_in[17];
    const float* if_b       = (const float*)d_in[18];
    float* out = (float*)d_out;

    char* ws = (char*)d_ws;
    float* Aemb  = (float*)ws;                       // 4096*96   (reused: logits+imp)
    float* xbuf  = (float*)(ws + 1572864);           // 4096*512  (reused: Pbuf/Hprev, then mo)
    float* xz    = (float*)(ws + 1572864 + 8388608);                       // 4096*2048
    float* xic   = (float*)(ws + 1572864 + 8388608 + 33554432);            // 4096*1024
    float* dbc   = (float*)(ws + 1572864 + 8388608 + 33554432 + 16777216); // 4096*64
    float* delta = (float*)(ws + 1572864 + 8388608 + 33554432 + 16777216 + 1048576); // 4096*1024
    float* yzb   = (float*)(ws + 1572864 + 8388608 + 33554432 + 16777216 + 1048576 + 16777216); // 4096*1024
    float* mo     = xbuf;   // xbuf dead after in_proj + scan carries
    float* logits = Aemb;   // Aemb dead after embed GEMM
    float* impb   = Aemb + 4096 * 10;
    float* Pbuf   = xbuf;   // 4*32*1024*16 floats = 8 MB, exactly xbuf's size
    float* Sbuf   = yzb;    // first 8 MB of yzb; dead before scan_p2 writes yzb
    float* Hprev  = Pbuf;   // scan_carry converts P -> incoming states in place

    // 1. im2col gather for embedding conv
    gather_embed<<<1536, NTHREADS, 0, stream>>>(x_enc, Aemb);
    // 2. embed GEMM: (4096x96) @ (512x96)^T -> x
    gemm_nt<<<dim3(64, 8), NTHREADS, 0, stream>>>(Aemb, 96, conv_w, 96, nullptr, xbuf, 512, 96, 0);
    // 3. += positional embedding
    posemb_add<<<8192, NTHREADS, 0, stream>>>(xbuf);
    // 4. in_proj: (4096x512) @ (2048x512)^T -> xz
    gemm_nt<<<dim3(64, 32), NTHREADS, 0, stream>>>(xbuf, 512, in_proj_w, 512, nullptr, xz, 2048, 512, 0);
    // 5. depthwise conv + SiLU -> xic
    dwconv_silu<<<16384, NTHREADS, 0, stream>>>(xz, conv1d_w, conv1d_b, xic);
    // 6. x_proj: (4096x1024) @ (64x1024)^T -> dbc
    gemm_nt<<<dim3(64, 1), NTHREADS, 0, stream>>>(xic, 1024, x_proj_w, 1024, nullptr, dbc, 64, 1024, 0);
    // 7. dt_proj + bias + softplus: (4096x32 of dbc) @ (1024x32)^T -> delta
    gemm_nt<<<dim3(64, 16), NTHREADS, 0, stream>>>(dbc, 64, dt_proj_w, 32, dt_proj_b, delta, 1024, 32, 1);
    // 8. chunked selective scan (3 kernels) -> yz
    scan_p1<<<512, NTHREADS, 0, stream>>>(delta, xic, dbc, A_log, Pbuf, Sbuf);
    scan_carry<<<16, NTHREADS, 0, stream>>>(Pbuf, Sbuf);
    scan_p2<<<512, NTHREADS, 0, stream>>>(delta, xic, dbc, xz, A_log, Dp, Hprev, yzb);
    // 9. out_proj: (4096x1024) @ (512x1024)^T -> mo
    gemm_nt<<<dim3(64, 8), NTHREADS, 0, stream>>>(yzb, 1024, out_proj_w, 1024, nullptr, mo, 512, 1024, 0);
    // 10. LayerNorm in place
    layernorm_ip<<<1024, NTHREADS, 0, stream>>>(mo, ln_w, ln_b);
    // 11. logits + importance per row
    head_k<<<1024, NTHREADS, 0, stream>>>(mo, out_layer_w, if_w, if_b, logits, impb);
    // 12. softmax pooling -> out (4,10)
    final_k<<<4, NTHREADS, 0, stream>>>(logits, impb, mark, out);
}

// Round 3
// 317.129 us; speedup vs baseline: 2.8326x; 1.3039x over previous
//
#include <hip/hip_runtime.h>
#include <math.h>

#define NTHREADS 256
#define NC 32   // scan chunks
#define CL 32   // chunk length (NC*CL = 1024)

typedef __attribute__((ext_vector_type(8))) short bf16x8;
typedef __attribute__((ext_vector_type(4))) float f32x4;

static __device__ __forceinline__ float siluf(float x) {
    return x / (1.f + __expf(-x));
}
static __device__ __forceinline__ float softplusf(float x) {
    return fmaxf(x, 0.f) + log1pf(__expf(-fabsf(x)));
}
static __device__ __forceinline__ unsigned short f2bf(float f) {
    unsigned int u = __float_as_uint(f);
    u = (u + 0x7fffu + ((u >> 16) & 1u)) >> 16;
    return (unsigned short)u;
}

// ---------------------------------------------------------------------------
// fp32 -> bf16 bulk convert (n multiple of 4)
__global__ __launch_bounds__(NTHREADS) void cvt_bf16(
    const float* __restrict__ in, unsigned short* __restrict__ out, int n4)
{
    int i = blockIdx.x * NTHREADS + threadIdx.x;
    if (i >= n4) return;
    float4 v = *(const float4*)(in + i * 4);
    ushort4 o;
    o.x = f2bf(v.x); o.y = f2bf(v.y); o.z = f2bf(v.z); o.w = f2bf(v.w);
    *(ushort4*)(out + i * 4) = o;
}

// ---------------------------------------------------------------------------
// Gather the im2col matrix for the embedding conv (edge-padded, k=3).
__global__ __launch_bounds__(NTHREADS) void gather_embed(
    const float* __restrict__ xe, float* __restrict__ Aemb)
{
    int idx = blockIdx.x * NTHREADS + threadIdx.x; // 4096*96
    int row = idx / 96, k = idx % 96;
    int c = k / 3, j = k % 3;
    int b = row >> 10, t = row & 1023;
    int tc = min(max(t + j - 2, 0), 1023);
    Aemb[idx] = xe[(b * 1024 + tc) * 32 + c];
}

// ---------------------------------------------------------------------------
// Generic fp32 GEMM: C[M,N] = A[M,K] @ B[N,K]^T (+bias)(+softplus)
__global__ __launch_bounds__(NTHREADS) void gemm_nt(
    const float* __restrict__ A, int lda,
    const float* __restrict__ B, int ldb,
    const float* __restrict__ bias,
    float* __restrict__ C, int ldc,
    int K, int act)
{
    __shared__ float As[16][68];
    __shared__ float Bs[16][68];
    const int tid = threadIdx.x;
    const int tx = tid & 15, ty = tid >> 4;
    const int m0 = blockIdx.x * 64, n0 = blockIdx.y * 64;
    const int lr = tid >> 2;
    const int lc = (tid & 3) << 2;
    float acc[4][4] = {{0.f}};
    const float* Ap = A + (m0 + lr) * lda + lc;
    const float* Bp = B + (n0 + lr) * ldb + lc;
    for (int k0 = 0; k0 < K; k0 += 16) {
        float4 av = *(const float4*)(Ap + k0);
        float4 bv = *(const float4*)(Bp + k0);
        __syncthreads();
        As[lc + 0][lr] = av.x; As[lc + 1][lr] = av.y;
        As[lc + 2][lr] = av.z; As[lc + 3][lr] = av.w;
        Bs[lc + 0][lr] = bv.x; Bs[lc + 1][lr] = bv.y;
        Bs[lc + 2][lr] = bv.z; Bs[lc + 3][lr] = bv.w;
        __syncthreads();
#pragma unroll
        for (int kk = 0; kk < 16; ++kk) {
            float4 a = *(const float4*)&As[kk][ty << 2];
            float4 b = *(const float4*)&Bs[kk][tx << 2];
            acc[0][0] += a.x * b.x; acc[0][1] += a.x * b.y;
            acc[0][2] += a.x * b.z; acc[0][3] += a.x * b.w;
            acc[1][0] += a.y * b.x; acc[1][1] += a.y * b.y;
            acc[1][2] += a.y * b.z; acc[1][3] += a.y * b.w;
            acc[2][0] += a.z * b.x; acc[2][1] += a.z * b.y;
            acc[2][2] += a.z * b.z; acc[2][3] += a.z * b.w;
            acc[3][0] += a.w * b.x; acc[3][1] += a.w * b.y;
            acc[3][2] += a.w * b.z; acc[3][3] += a.w * b.w;
        }
    }
#pragma unroll
    for (int i = 0; i < 4; ++i) {
        int mrow = m0 + (ty << 2) + i;
#pragma unroll
        for (int j = 0; j < 4; ++j) {
            int ncol = n0 + (tx << 2) + j;
            float v = acc[i][j];
            if (bias) v += bias[ncol];
            if (act == 1) v = softplusf(v);
            C[mrow * ldc + ncol] = v;
        }
    }
}

// ---------------------------------------------------------------------------
// bf16 MFMA GEMM: C[M,N](fp32) = A[M,K](bf16) @ B[N,K](bf16)^T
// 128x128 tile, BK=64, 256 threads = 4 waves (2x2), XOR-swizzled LDS.
__global__ __launch_bounds__(NTHREADS) void gemm_bf16(
    const unsigned short* __restrict__ A,
    const unsigned short* __restrict__ B,
    float* __restrict__ C,
    int N, int K)
{
    __shared__ __align__(16) unsigned short lds[2 * 128 * 64]; // A tile | B tile
    char* Ab = (char*)lds;
    char* Bb = (char*)lds + 128 * 64 * 2;

    const int tid = threadIdx.x;
    const int lane = tid & 63;
    const int w = tid >> 6;
    const int wr = w >> 1, wc = w & 1;
    const int m0 = blockIdx.x * 128, n0 = blockIdx.y * 128;

    // staging: thread covers rows rt, rt+32, rt+64, rt+96 at 16B chunk c16
    const int rt = tid >> 3;
    const int c16 = tid & 7;
    const int wbyte = (c16 * 16) ^ ((rt & 7) << 4);

    f32x4 acc[4][4] = {};
    const size_t aoff = (size_t)(m0 + rt) * K + c16 * 8;

    for (int k0 = 0; k0 < K; k0 += 64) {
        uint4 ra[4], rb[4];
#pragma unroll
        for (int p = 0; p < 4; ++p) {
            ra[p] = *(const uint4*)(A + aoff + (size_t)p * 32 * K + k0);
            int brow = n0 + rt + p * 32;
            if (brow >= N) brow = N - 1;
            rb[p] = *(const uint4*)(B + (size_t)brow * K + k0 + c16 * 8);
        }
        __syncthreads();   // previous tile's reads complete
#pragma unroll
        for (int p = 0; p < 4; ++p) {
            *(uint4*)(Ab + (rt + p * 32) * 128 + wbyte) = ra[p];
            *(uint4*)(Bb + (rt + p * 32) * 128 + wbyte) = rb[p];
        }
        __syncthreads();   // tile ready
#pragma unroll
        for (int kk = 0; kk < 2; ++kk) {
            const int kb = kk * 64 + ((lane >> 4) << 4);   // byte offset in row
            const int rxor = (lane & 7) << 4;
            bf16x8 af[4], bfr[4];
#pragma unroll
            for (int i = 0; i < 4; ++i) {
                int arow = wr * 64 + i * 16 + (lane & 15);
                af[i] = *(const bf16x8*)(Ab + arow * 128 + (kb ^ rxor));
                int brow = wc * 64 + i * 16 + (lane & 15);
                bfr[i] = *(const bf16x8*)(Bb + brow * 128 + (kb ^ rxor));
            }
#pragma unroll
            for (int i = 0; i < 4; ++i)
#pragma unroll
                for (int j = 0; j < 4; ++j)
                    acc[i][j] = __builtin_amdgcn_mfma_f32_16x16x32_bf16(
                        af[i], bfr[j], acc[i][j], 0, 0, 0);
        }
    }
#pragma unroll
    for (int i = 0; i < 4; ++i) {
        int mrow = m0 + wr * 64 + i * 16 + ((lane >> 4) << 2);
#pragma unroll
        for (int j = 0; j < 4; ++j) {
            int ncol = n0 + wc * 64 + j * 16 + (lane & 15);
            if (ncol < N) {
#pragma unroll
                for (int r = 0; r < 4; ++r)
                    C[(size_t)(mrow + r) * N + ncol] = acc[i][j][r];
            }
        }
    }
}

// ---------------------------------------------------------------------------
// x + positional embedding -> bf16 (consumed by in_proj MFMA GEMM)
__global__ __launch_bounds__(NTHREADS) void posemb_bf(
    const float* __restrict__ x, unsigned short* __restrict__ out)
{
    int i4 = blockIdx.x * NTHREADS + threadIdx.x;   // 4096*512/4
    int row = i4 >> 7;
    int d0 = (i4 & 127) * 4;
    int t = row & 1023;
    const float lf = 9.210340372f / 512.f;          // ln(10000)/512
    float4 v = *(const float4*)(x + (size_t)row * 512 + d0);
    float f0 = __expf(-(float)d0 * lf);
    float f1 = __expf(-(float)(d0 + 2) * lf);
    float a0 = (float)t * f0, a1 = (float)t * f1;
    v.x += sinf(a0); v.y += cosf(a0);
    v.z += sinf(a1); v.w += cosf(a1);
    ushort4 o;
    o.x = f2bf(v.x); o.y = f2bf(v.y); o.z = f2bf(v.z); o.w = f2bf(v.w);
    *(ushort4*)(out + (size_t)i4 * 4) = o;
}

// ---------------------------------------------------------------------------
// Depthwise causal conv1d + bias + SiLU -> fp32 (scan) and bf16 (x_proj GEMM)
__global__ __launch_bounds__(NTHREADS) void dwconv_silu(
    const float* __restrict__ xz, const float* __restrict__ w,
    const float* __restrict__ bias, float* __restrict__ out,
    unsigned short* __restrict__ outbf)
{
    int idx = blockIdx.x * NTHREADS + threadIdx.x; // 4096*1024
    int row = idx >> 10;
    int d = idx & 1023;
    int b = row >> 10, l = row & 1023;
    float acc = bias[d];
#pragma unroll
    for (int j = 0; j < 4; ++j) {
        int ls = l - 3 + j;
        if (ls >= 0) acc += xz[(b * 1024 + ls) * 2048 + d] * w[d * 4 + j];
    }
    float s = siluf(acc);
    out[idx] = s;
    outbf[idx] = f2bf(s);
}

// ---------------------------------------------------------------------------
// Chunked selective scan, pass 1.
__global__ __launch_bounds__(NTHREADS) void scan_p1(
    const float* __restrict__ delta, const float* __restrict__ xic,
    const float* __restrict__ dbc, const float* __restrict__ A_log,
    float* __restrict__ Pbuf, float* __restrict__ Sbuf)
{
    int blk = blockIdx.x;              // ((b*NC + c)*4 + g)
    int g = blk & 3;
    int c = (blk >> 2) & (NC - 1);
    int b = blk >> 7;
    int d = (g << 8) + threadIdx.x;
    float Ac[16];
#pragma unroll
    for (int s = 0; s < 16; s += 4) {
        float4 v = *(const float4*)(A_log + d * 16 + s);
        Ac[s + 0] = -expf(v.x); Ac[s + 1] = -expf(v.y);
        Ac[s + 2] = -expf(v.z); Ac[s + 3] = -expf(v.w);
    }
    float a[16], h[16];
#pragma unroll
    for (int s = 0; s < 16; ++s) { a[s] = 1.f; h[s] = 0.f; }
    int base = b * 1024 + c * CL;
    for (int l = 0; l < CL; ++l) {
        int row = base + l;
        float dl = delta[row * 1024 + d];
        float xv = xic[row * 1024 + d];
        const float* bc = dbc + row * 64 + 32;
        float dxi = dl * xv;
#pragma unroll
        for (int s = 0; s < 16; s += 4) {
            float4 bV = *(const float4*)(bc + s);
            float dA0 = __expf(dl * Ac[s + 0]);
            float dA1 = __expf(dl * Ac[s + 1]);
            float dA2 = __expf(dl * Ac[s + 2]);
            float dA3 = __expf(dl * Ac[s + 3]);
            a[s + 0] *= dA0; h[s + 0] = dA0 * h[s + 0] + dxi * bV.x;
            a[s + 1] *= dA1; h[s + 1] = dA1 * h[s + 1] + dxi * bV.y;
            a[s + 2] *= dA2; h[s + 2] = dA2 * h[s + 2] + dxi * bV.z;
            a[s + 3] *= dA3; h[s + 3] = dA3 * h[s + 3] + dxi * bV.w;
        }
    }
    int off = ((b * NC + c) * 1024 + d) * 16;
#pragma unroll
    for (int s = 0; s < 16; s += 4) {
        *(float4*)(Pbuf + off + s) = make_float4(a[s], a[s + 1], a[s + 2], a[s + 3]);
        *(float4*)(Sbuf + off + s) = make_float4(h[s], h[s + 1], h[s + 2], h[s + 3]);
    }
}

// ---------------------------------------------------------------------------
// Carry combine across chunks (writes incoming states over Pbuf in place).
__global__ __launch_bounds__(NTHREADS) void scan_carry(
    float* __restrict__ Pbuf, const float* __restrict__ Sbuf)
{
    int b = blockIdx.x >> 2;
    int d = ((blockIdx.x & 3) << 8) + threadIdx.x;
    float H[16];
#pragma unroll
    for (int s = 0; s < 16; ++s) H[s] = 0.f;
    for (int c = 0; c < NC; ++c) {
        int off = ((b * NC + c) * 1024 + d) * 16;
        float P[16], S[16];
#pragma unroll
        for (int s = 0; s < 16; s += 4) {
            float4 pv = *(const float4*)(Pbuf + off + s);
            float4 sv = *(const float4*)(Sbuf + off + s);
            P[s] = pv.x; P[s + 1] = pv.y; P[s + 2] = pv.z; P[s + 3] = pv.w;
            S[s] = sv.x; S[s + 1] = sv.y; S[s + 2] = sv.z; S[s + 3] = sv.w;
        }
#pragma unroll
        for (int s = 0; s < 16; s += 4)
            *(float4*)(Pbuf + off + s) = make_float4(H[s], H[s + 1], H[s + 2], H[s + 3]);
#pragma unroll
        for (int s = 0; s < 16; ++s) H[s] = P[s] * H[s] + S[s];
    }
}

// ---------------------------------------------------------------------------
// Pass 2: re-run chunk from true incoming state; emit gated output as bf16.
__global__ __launch_bounds__(NTHREADS) void scan_p2(
    const float* __restrict__ delta, const float* __restrict__ xic,
    const float* __restrict__ dbc, const float* __restrict__ xz,
    const float* __restrict__ A_log, const float* __restrict__ Dp,
    const float* __restrict__ Hprev, unsigned short* __restrict__ yz)
{
    int blk = blockIdx.x;
    int g = blk & 3;
    int c = (blk >> 2) & (NC - 1);
    int b = blk >> 7;
    int d = (g << 8) + threadIdx.x;
    float Ac[16];
#pragma unroll
    for (int s = 0; s < 16; s += 4) {
        float4 v = *(const float4*)(A_log + d * 16 + s);
        Ac[s + 0] = -expf(v.x); Ac[s + 1] = -expf(v.y);
        Ac[s + 2] = -expf(v.z); Ac[s + 3] = -expf(v.w);
    }
    float dp = Dp[d];
    float h[16];
    int off = ((b * NC + c) * 1024 + d) * 16;
#pragma unroll
    for (int s = 0; s < 16; s += 4) {
        float4 hv = *(const float4*)(Hprev + off + s);
        h[s] = hv.x; h[s + 1] = hv.y; h[s + 2] = hv.z; h[s + 3] = hv.w;
    }
    int base = b * 1024 + c * CL;
    for (int l = 0; l < CL; ++l) {
        int row = base + l;
        float dl = delta[row * 1024 + d];
        float xv = xic[row * 1024 + d];
        float zv = xz[row * 2048 + 1024 + d];
        const float* bc = dbc + row * 64;
        float dxi = dl * xv;
        float y = 0.f;
#pragma unroll
        for (int s = 0; s < 16; s += 4) {
            float4 bV = *(const float4*)(bc + 32 + s);
            float4 cV = *(const float4*)(bc + 48 + s);
            float dA0 = __expf(dl * Ac[s + 0]);
            float dA1 = __expf(dl * Ac[s + 1]);
            float dA2 = __expf(dl * Ac[s + 2]);
            float dA3 = __expf(dl * Ac[s + 3]);
            h[s + 0] = dA0 * h[s + 0] + dxi * bV.x;
            h[s + 1] = dA1 * h[s + 1] + dxi * bV.y;
            h[s + 2] = dA2 * h[s + 2] + dxi * bV.z;
            h[s + 3] = dA3 * h[s + 3] + dxi * bV.w;
            y += h[s + 0] * cV.x + h[s + 1] * cV.y + h[s + 2] * cV.z + h[s + 3] * cV.w;
        }
        y += xv * dp;
        yz[row * 1024 + d] = f2bf(y * siluf(zv));
    }
}

// ---------------------------------------------------------------------------
__global__ __launch_bounds__(NTHREADS) void layernorm_ip(
    float* __restrict__ mo, const float* __restrict__ w, const float* __restrict__ bvec)
{
    int wv = threadIdx.x >> 6, lane = threadIdx.x & 63;
    int row = (blockIdx.x << 2) + wv;
    float* p = mo + row * 512;
    float4 v0 = ((const float4*)p)[lane];
    float4 v1 = ((const float4*)p)[lane + 64];
    float s = v0.x + v0.y + v0.z + v0.w + v1.x + v1.y + v1.z + v1.w;
    float q = v0.x * v0.x + v0.y * v0.y + v0.z * v0.z + v0.w * v0.w
            + v1.x * v1.x + v1.y * v1.y + v1.z * v1.z + v1.w * v1.w;
#pragma unroll
    for (int off = 32; off; off >>= 1) {
        s += __shfl_xor(s, off);
        q += __shfl_xor(q, off);
    }
    float mean = s * (1.f / 512.f);
    float var = q * (1.f / 512.f) - mean * mean;
    float rstd = rsqrtf(var + 1e-5f);
    float4 w0 = ((const float4*)w)[lane], w1 = ((const float4*)w)[lane + 64];
    float4 b0 = ((const float4*)bvec)[lane], b1 = ((const float4*)bvec)[lane + 64];
    v0.x = (v0.x - mean) * rstd * w0.x + b0.x;
    v0.y = (v0.y - mean) * rstd * w0.y + b0.y;
    v0.z = (v0.z - mean) * rstd * w0.z + b0.z;
    v0.w = (v0.w - mean) * rstd * w0.w + b0.w;
    v1.x = (v1.x - mean) * rstd * w1.x + b1.x;
    v1.y = (v1.y - mean) * rstd * w1.y + b1.y;
    v1.z = (v1.z - mean) * rstd * w1.z + b1.z;
    v1.w = (v1.w - mean) * rstd * w1.w + b1.w;
    ((float4*)p)[lane] = v0;
    ((float4*)p)[lane + 64] = v1;
}

// ---------------------------------------------------------------------------
__global__ __launch_bounds__(NTHREADS) void head_k(
    const float* __restrict__ mo, const float* __restrict__ Wc,
    const float* __restrict__ ifw, const float* __restrict__ ifb,
    float* __restrict__ logits, float* __restrict__ imp)
{
    int wv = threadIdx.x >> 6, lane = threadIdx.x & 63;
    int row = (blockIdx.x << 2) + wv;
    const float* p = mo + row * 512 + lane * 8;
    float4 x0 = *(const float4*)p;
    float4 x1 = *(const float4*)(p + 4);
    float part[11];
#pragma unroll
    for (int c = 0; c < 10; ++c) {
        const float* wr = Wc + c * 512 + lane * 8;
        float4 w0 = *(const float4*)wr, w1 = *(const float4*)(wr + 4);
        part[c] = x0.x * w0.x + x0.y * w0.y + x0.z * w0.z + x0.w * w0.w
                + x1.x * w1.x + x1.y * w1.y + x1.z * w1.z + x1.w * w1.w;
    }
    {
        const float* wr = ifw + lane * 8;
        float4 w0 = *(const float4*)wr, w1 = *(const float4*)(wr + 4);
        part[10] = x0.x * w0.x + x0.y * w0.y + x0.z * w0.z + x0.w * w0.w
                 + x1.x * w1.x + x1.y * w1.y + x1.z * w1.z + x1.w * w1.w;
    }
#pragma unroll
    for (int i = 0; i < 11; ++i)
#pragma unroll
        for (int off = 32; off; off >>= 1) part[i] += __shfl_xor(part[i], off);
    if (lane == 0) {
#pragma unroll
        for (int c = 0; c < 10; ++c) logits[row * 10 + c] = part[c];
        imp[row] = part[10] + ifb[0];
    }
}

// ---------------------------------------------------------------------------
__global__ __launch_bounds__(NTHREADS) void final_k(
    const float* __restrict__ logits, const float* __restrict__ imp,
    const float* __restrict__ mark, float* __restrict__ out)
{
    __shared__ float sred[4];
    int b = blockIdx.x, tid = threadIdx.x;
    int wv = tid >> 6, lane = tid & 63;
    float m = -1e30f;
    for (int l = tid; l < 1024; l += NTHREADS) m = fmaxf(m, imp[b * 1024 + l]);
#pragma unroll
    for (int off = 32; off; off >>= 1) m = fmaxf(m, __shfl_xor(m, off));
    if (lane == 0) sred[wv] = m;
    __syncthreads();
    m = fmaxf(fmaxf(sred[0], sred[1]), fmaxf(sred[2], sred[3]));
    __syncthreads();
    float den = 0.f, num[10];
#pragma unroll
    for (int c = 0; c < 10; ++c) num[c] = 0.f;
    for (int l = tid; l < 1024; l += NTHREADS) {
        float e = __expf(imp[b * 1024 + l] - m);
        float mk = mark[b * 1024 + l];
        den += e * mk;
        float w2 = e * mk * mk;
        const float* lg = logits + (b * 1024 + l) * 10;
#pragma unroll
        for (int c = 0; c < 10; ++c) num[c] += lg[c] * w2;
    }
#pragma unroll
    for (int off = 32; off; off >>= 1) den += __shfl_xor(den, off);
    if (lane == 0) sred[wv] = den;
    __syncthreads();
    den = sred[0] + sred[1] + sred[2] + sred[3];
    __syncthreads();
#pragma unroll
    for (int c = 0; c < 10; ++c) {
        float v = num[c];
#pragma unroll
        for (int off = 32; off; off >>= 1) v += __shfl_xor(v, off);
        if (lane == 0) sred[wv] = v;
        __syncthreads();
        v = sred[0] + sred[1] + sred[2] + sred[3];
        __syncthreads();
        num[c] = v;
    }
    if (tid == 0) {
        float inv = 1.f / den;
#pragma unroll
        for (int c = 0; c < 10; ++c) out[b * 10 + c] = num[c] * inv;
    }
}

// ---------------------------------------------------------------------------
extern "C" void kernel_launch(void* const* d_in, const int* in_sizes, int n_in,
                              void* d_out, int out_size, void* d_ws, size_t ws_size,
                              hipStream_t stream) {
    (void)in_sizes; (void)n_in; (void)out_size; (void)ws_size;
    const float* x_enc      = (const float*)d_in[0];
    const float* mark       = (const float*)d_in[1];
    const float* conv_w     = (const float*)d_in[4];
    const float* in_proj_w  = (const float*)d_in[5];
    const float* conv1d_w   = (const float*)d_in[6];
    const float* conv1d_b   = (const float*)d_in[7];
    const float* x_proj_w   = (const float*)d_in[8];
    const float* dt_proj_w  = (const float*)d_in[9];
    const float* dt_proj_b  = (const float*)d_in[10];
    const float* A_log      = (const float*)d_in[11];
    const float* Dp         = (const float*)d_in[12];
    const float* out_proj_w = (const float*)d_in[13];
    const float* ln_w       = (const float*)d_in[14];
    const float* ln_b       = (const float*)d_in[15];
    const float* out_layer_w= (const float*)d_in[16];
    const float* if_w       = (const float*)d_in[17];
    const float* if_b       = (const float*)d_in[18];
    float* out = (float*)d_out;

    // ---- workspace layout (bytes) ----
    char* ws = (char*)d_ws;
    float* Aemb    = (float*)(ws + 0);          // 1,572,864  (later: logits/imp)
    float* xbuf    = (float*)(ws + 1572864);    // 8,388,608  (later: mo)
    float* xz      = (float*)(ws + 9961472);    // 33,554,432
    float* xic     = (float*)(ws + 43515904);   // 16,777,216 (first 2MB first used as Wip_bf)
    float* dbc     = (float*)(ws + 60293120);   // 1,048,576
    float* delta   = (float*)(ws + 61341696);   // 16,777,216 (first 4MB first used as Abf)
    float* scratch = (float*)(ws + 78118912);   // 16,777,216 (Xibf 8MB; then P|S; S later Ybf)
    unsigned short* Wxp_bf = (unsigned short*)(ws + 94896128);  // 131,072
    unsigned short* Wop_bf = (unsigned short*)(ws + 95027200);  // 1,048,576
    // aliases
    unsigned short* Abf   = (unsigned short*)delta;     // 4MB, dead before dt_proj writes delta
    unsigned short* Wip_bf= (unsigned short*)xic;       // 2MB, dead before dwconv writes xic
    unsigned short* Xibf  = (unsigned short*)scratch;   // 8MB, dead before scan_p1 writes P/S
    float* Pbuf   = scratch;                            // 8MB
    float* Sbuf   = scratch + 2097152;                  // 8MB
    float* Hprev  = Pbuf;                               // carry in place
    unsigned short* Ybf = (unsigned short*)Sbuf;        // 8MB, S dead after carry
    float* mo     = xbuf;
    float* logits = Aemb;
    float* impb   = Aemb + 4096 * 10;

    // 1. weight conversions (independent)
    cvt_bf16<<<1024, NTHREADS, 0, stream>>>(in_proj_w, Wip_bf, 262144);
    cvt_bf16<<<64,   NTHREADS, 0, stream>>>(x_proj_w,  Wxp_bf, 16384);
    cvt_bf16<<<512,  NTHREADS, 0, stream>>>(out_proj_w, Wop_bf, 131072);
    // 2. im2col gather + embed GEMM (fp32): (4096x96) @ (512x96)^T -> xbuf
    gather_embed<<<1536, NTHREADS, 0, stream>>>(x_enc, Aemb);
    gemm_nt<<<dim3(64, 8), NTHREADS, 0, stream>>>(Aemb, 96, conv_w, 96, nullptr, xbuf, 512, 96, 0);
    // 3. + positional embedding -> bf16 A
    posemb_bf<<<2048, NTHREADS, 0, stream>>>(xbuf, Abf);
    // 4. in_proj (MFMA): (4096x512) @ (2048x512)^T -> xz
    gemm_bf16<<<dim3(32, 16), NTHREADS, 0, stream>>>(Abf, Wip_bf, xz, 2048, 512);
    // 5. depthwise conv + SiLU -> xic (fp32) + Xibf (bf16)
    dwconv_silu<<<16384, NTHREADS, 0, stream>>>(xz, conv1d_w, conv1d_b, xic, Xibf);
    // 6. x_proj (MFMA): (4096x1024) @ (64x1024)^T -> dbc
    gemm_bf16<<<dim3(32, 1), NTHREADS, 0, stream>>>(Xibf, Wxp_bf, dbc, 64, 1024);
    // 7. dt_proj + bias + softplus (fp32): -> delta
    gemm_nt<<<dim3(64, 16), NTHREADS, 0, stream>>>(dbc, 64, dt_proj_w, 32, dt_proj_b, delta, 1024, 32, 1);
    // 8. chunked selective scan -> Ybf (bf16)
    scan_p1<<<512, NTHREADS, 0, stream>>>(delta, xic, dbc, A_log, Pbuf, Sbuf);
    scan_carry<<<16, NTHREADS, 0, stream>>>(Pbuf, Sbuf);
    scan_p2<<<512, NTHREADS, 0, stream>>>(delta, xic, dbc, xz, A_log, Dp, Hprev, Ybf);
    // 9. out_proj (MFMA): (4096x1024) @ (512x1024)^T -> mo
    gemm_bf16<<<dim3(32, 4), NTHREADS, 0, stream>>>(Ybf, Wop_bf, mo, 512, 1024);
    // 10-12. LayerNorm, heads, pooling
    layernorm_ip<<<1024, NTHREADS, 0, stream>>>(mo, ln_w, ln_b);
    head_k<<<1024, NTHREADS, 0, stream>>>(mo, out_layer_w, if_w, if_b, logits, impb);
    final_k<<<4, NTHREADS, 0, stream>>>(logits, impb, mark, out);
}

// Round 4
// 268.135 us; speedup vs baseline: 3.3502x; 1.1827x over previous
//
#include <hip/hip_runtime.h>
#include <math.h>

#define NTHREADS 256
#define NC 32   // scan chunks
#define CL 32   // chunk length (NC*CL = 1024)

typedef __attribute__((ext_vector_type(8))) short bf16x8;
typedef __attribute__((ext_vector_type(4))) float f32x4;

static __device__ __forceinline__ float siluf(float x) {
    return x / (1.f + __expf(-x));
}
static __device__ __forceinline__ float softplusf(float x) {
    return fmaxf(x, 0.f) + log1pf(__expf(-fabsf(x)));
}
static __device__ __forceinline__ unsigned short f2bf(float f) {
    unsigned int u = __float_as_uint(f);
    u = (u + 0x7fffu + ((u >> 16) & 1u)) >> 16;
    return (unsigned short)u;
}

// ---------------------------------------------------------------------------
// fp32 -> bf16 bulk convert (n4 = count of float4 groups)
__global__ __launch_bounds__(NTHREADS) void cvt_bf16(
    const float* __restrict__ in, unsigned short* __restrict__ out, int n4)
{
    int i = blockIdx.x * NTHREADS + threadIdx.x;
    if (i >= n4) return;
    float4 v = *(const float4*)(in + i * 4);
    ushort4 o;
    o.x = f2bf(v.x); o.y = f2bf(v.y); o.z = f2bf(v.z); o.w = f2bf(v.w);
    *(ushort4*)(out + i * 4) = o;
}

// ---------------------------------------------------------------------------
// Gather the im2col matrix for the embedding conv (edge-padded, k=3).
__global__ __launch_bounds__(NTHREADS) void gather_embed(
    const float* __restrict__ xe, float* __restrict__ Aemb)
{
    int idx = blockIdx.x * NTHREADS + threadIdx.x; // 4096*96
    int row = idx / 96, k = idx % 96;
    int c = k / 3, j = k % 3;
    int b = row >> 10, t = row & 1023;
    int tc = min(max(t + j - 2, 0), 1023);
    Aemb[idx] = xe[(b * 1024 + tc) * 32 + c];
}

// ---------------------------------------------------------------------------
// Generic fp32 GEMM: C[M,N] = A[M,K] @ B[N,K]^T (+bias)(+softplus)
__global__ __launch_bounds__(NTHREADS) void gemm_nt(
    const float* __restrict__ A, int lda,
    const float* __restrict__ B, int ldb,
    const float* __restrict__ bias,
    float* __restrict__ C, int ldc,
    int K, int act)
{
    __shared__ float As[16][68];
    __shared__ float Bs[16][68];
    const int tid = threadIdx.x;
    const int tx = tid & 15, ty = tid >> 4;
    const int m0 = blockIdx.x * 64, n0 = blockIdx.y * 64;
    const int lr = tid >> 2;
    const int lc = (tid & 3) << 2;
    float acc[4][4] = {{0.f}};
    const float* Ap = A + (m0 + lr) * lda + lc;
    const float* Bp = B + (n0 + lr) * ldb + lc;
    for (int k0 = 0; k0 < K; k0 += 16) {
        float4 av = *(const float4*)(Ap + k0);
        float4 bv = *(const float4*)(Bp + k0);
        __syncthreads();
        As[lc + 0][lr] = av.x; As[lc + 1][lr] = av.y;
        As[lc + 2][lr] = av.z; As[lc + 3][lr] = av.w;
        Bs[lc + 0][lr] = bv.x; Bs[lc + 1][lr] = bv.y;
        Bs[lc + 2][lr] = bv.z; Bs[lc + 3][lr] = bv.w;
        __syncthreads();
#pragma unroll
        for (int kk = 0; kk < 16; ++kk) {
            float4 a = *(const float4*)&As[kk][ty << 2];
            float4 b = *(const float4*)&Bs[kk][tx << 2];
            acc[0][0] += a.x * b.x; acc[0][1] += a.x * b.y;
            acc[0][2] += a.x * b.z; acc[0][3] += a.x * b.w;
            acc[1][0] += a.y * b.x; acc[1][1] += a.y * b.y;
            acc[1][2] += a.y * b.z; acc[1][3] += a.y * b.w;
            acc[2][0] += a.z * b.x; acc[2][1] += a.z * b.y;
            acc[2][2] += a.z * b.z; acc[2][3] += a.z * b.w;
            acc[3][0] += a.w * b.x; acc[3][1] += a.w * b.y;
            acc[3][2] += a.w * b.z; acc[3][3] += a.w * b.w;
        }
    }
#pragma unroll
    for (int i = 0; i < 4; ++i) {
        int mrow = m0 + (ty << 2) + i;
#pragma unroll
        for (int j = 0; j < 4; ++j) {
            int ncol = n0 + (tx << 2) + j;
            float v = acc[i][j];
            if (bias) v += bias[ncol];
            if (act == 1) v = softplusf(v);
            C[mrow * ldc + ncol] = v;
        }
    }
}

// ---------------------------------------------------------------------------
// bf16 MFMA GEMM (templated): C[M,N](fp32) = A[M,K](bf16) @ B[N,K](bf16)^T
// Swapped-operand MFMA so each lane holds 4 consecutive C columns -> f32x4
// stores. Register-prefetch of next K-tile overlaps ds_read+MFMA phase.
// KSPLIT>1 writes partials at blockIdx.z*partStride (reduced separately).
template<int BM, int BN, int KSPLIT>
__global__ __launch_bounds__(NTHREADS) void gemm_bf16_t(
    const unsigned short* __restrict__ A,
    const unsigned short* __restrict__ B,
    float* __restrict__ C, int N, int K, long long partStride)
{
    constexpr int WRN = (BN == 128) ? 2 : 1;   // waves along N
    constexpr int WRM = 4 / WRN;               // waves along M
    constexpr int WTM = BM / WRM;              // wave tile M (64 or 32)
    constexpr int WTN = BN / WRN;              // wave tile N (64)
    constexpr int FI = WTM / 16;
    constexpr int FJ = WTN / 16;
    constexpr int PA = BM / 32;                // staging passes for A
    constexpr int PB = BN / 32;

    __shared__ __align__(16) char lds[(BM + BN) * 128];
    char* Ab = lds;
    char* Bb = lds + BM * 128;

    const int tid = threadIdx.x;
    const int lane = tid & 63;
    const int w = tid >> 6;
    const int wr = w / WRN, wc = w % WRN;
    const int m0 = blockIdx.x * BM, n0 = blockIdx.y * BN;
    const int kper = K / KSPLIT;
    const int kbeg = blockIdx.z * kper;

    // staging: thread covers rows rt+32p at 16B chunk c16, XOR-swizzled
    const int rt = tid >> 3;
    const int c16 = tid & 7;
    const int wbyte = (c16 * 16) ^ ((rt & 7) << 4);

    f32x4 acc[FI][FJ] = {};

    const unsigned short* Ap = A + (size_t)(m0 + rt) * K + kbeg + c16 * 8;
    const unsigned short* Bp = B + (size_t)(n0 + rt) * K + kbeg + c16 * 8;

    uint4 ra[PA], rb[PB];
#pragma unroll
    for (int p = 0; p < PA; ++p) ra[p] = *(const uint4*)(Ap + (size_t)p * 32 * K);
#pragma unroll
    for (int p = 0; p < PB; ++p) rb[p] = *(const uint4*)(Bp + (size_t)p * 32 * K);

    for (int k0 = 0; k0 < kper; k0 += 64) {
        __syncthreads();   // previous tile's LDS reads complete
#pragma unroll
        for (int p = 0; p < PA; ++p) *(uint4*)(Ab + (rt + p * 32) * 128 + wbyte) = ra[p];
#pragma unroll
        for (int p = 0; p < PB; ++p) *(uint4*)(Bb + (rt + p * 32) * 128 + wbyte) = rb[p];
        __syncthreads();   // tile ready
        if (k0 + 64 < kper) {  // prefetch next tile; latency hides under MFMA
#pragma unroll
            for (int p = 0; p < PA; ++p) ra[p] = *(const uint4*)(Ap + (size_t)p * 32 * K + k0 + 64);
#pragma unroll
            for (int p = 0; p < PB; ++p) rb[p] = *(const uint4*)(Bp + (size_t)p * 32 * K + k0 + 64);
        }
#pragma unroll
        for (int kk = 0; kk < 2; ++kk) {
            const int kb = kk * 64 + ((lane >> 4) << 4);
            const int rxor = (lane & 7) << 4;
            bf16x8 af[FI], bfr[FJ];
#pragma unroll
            for (int i = 0; i < FI; ++i) {
                int arow = wr * WTM + i * 16 + (lane & 15);
                af[i] = *(const bf16x8*)(Ab + arow * 128 + (kb ^ rxor));
            }
#pragma unroll
            for (int j = 0; j < FJ; ++j) {
                int brow = wc * WTN + j * 16 + (lane & 15);
                bfr[j] = *(const bf16x8*)(Bb + brow * 128 + (kb ^ rxor));
            }
#pragma unroll
            for (int i = 0; i < FI; ++i)
#pragma unroll
                for (int j = 0; j < FJ; ++j)
                    acc[i][j] = __builtin_amdgcn_mfma_f32_16x16x32_bf16(
                        bfr[j], af[i], acc[i][j], 0, 0, 0);   // swapped -> C^T frag
        }
    }
    float* Cp = C + (long long)blockIdx.z * partStride;
#pragma unroll
    for (int i = 0; i < FI; ++i) {
        int row = m0 + wr * WTM + i * 16 + (lane & 15);
#pragma unroll
        for (int j = 0; j < FJ; ++j) {
            int col = n0 + wc * WTN + j * 16 + ((lane >> 4) << 2);
            *(f32x4*)(Cp + (size_t)row * N + col) = acc[i][j];
        }
    }
}

// ---------------------------------------------------------------------------
// Reduce split-K partials: out[i] = sum_z part[z*stride + i]  (float4 lanes)
__global__ __launch_bounds__(NTHREADS) void reduce_k8(
    const float* __restrict__ part, float* __restrict__ out)
{
    int i = blockIdx.x * NTHREADS + threadIdx.x;   // 65536 float4 groups
    const size_t stride = 4096 * 64;
    float4 s = *(const float4*)(part + (size_t)i * 4);
#pragma unroll
    for (int z = 1; z < 8; ++z) {
        float4 v = *(const float4*)(part + z * stride + (size_t)i * 4);
        s.x += v.x; s.y += v.y; s.z += v.z; s.w += v.w;
    }
    *(float4*)(out + (size_t)i * 4) = s;
}

// ---------------------------------------------------------------------------
// x + positional embedding -> bf16 (consumed by in_proj MFMA GEMM)
__global__ __launch_bounds__(NTHREADS) void posemb_bf(
    const float* __restrict__ x, unsigned short* __restrict__ out)
{
    int i4 = blockIdx.x * NTHREADS + threadIdx.x;   // 4096*512/4
    int row = i4 >> 7;
    int d0 = (i4 & 127) * 4;
    int t = row & 1023;
    const float lf = 9.210340372f / 512.f;          // ln(10000)/512
    float4 v = *(const float4*)(x + (size_t)row * 512 + d0);
    float f0 = __expf(-(float)d0 * lf);
    float f1 = __expf(-(float)(d0 + 2) * lf);
    float a0 = (float)t * f0, a1 = (float)t * f1;
    v.x += sinf(a0); v.y += cosf(a0);
    v.z += sinf(a1); v.w += cosf(a1);
    ushort4 o;
    o.x = f2bf(v.x); o.y = f2bf(v.y); o.z = f2bf(v.z); o.w = f2bf(v.w);
    *(ushort4*)(out + (size_t)i4 * 4) = o;
}

// ---------------------------------------------------------------------------
// Depthwise causal conv1d + bias + SiLU -> fp32 (scan) and bf16 (x_proj GEMM)
__global__ __launch_bounds__(NTHREADS) void dwconv_silu(
    const float* __restrict__ xz, const float* __restrict__ w,
    const float* __restrict__ bias, float* __restrict__ out,
    unsigned short* __restrict__ outbf)
{
    int idx = blockIdx.x * NTHREADS + threadIdx.x; // 4096*1024
    int row = idx >> 10;
    int d = idx & 1023;
    int b = row >> 10, l = row & 1023;
    float acc = bias[d];
#pragma unroll
    for (int j = 0; j < 4; ++j) {
        int ls = l - 3 + j;
        if (ls >= 0) acc += xz[(b * 1024 + ls) * 2048 + d] * w[d * 4 + j];
    }
    float s = siluf(acc);
    out[idx] = s;
    outbf[idx] = f2bf(s);
}

// ---------------------------------------------------------------------------
// Chunked selective scan, pass 1.
__global__ __launch_bounds__(NTHREADS) void scan_p1(
    const float* __restrict__ delta, const float* __restrict__ xic,
    const float* __restrict__ dbc, const float* __restrict__ A_log,
    float* __restrict__ Pbuf, float* __restrict__ Sbuf)
{
    int blk = blockIdx.x;              // ((b*NC + c)*4 + g)
    int g = blk & 3;
    int c = (blk >> 2) & (NC - 1);
    int b = blk >> 7;
    int d = (g << 8) + threadIdx.x;
    float Ac[16];
#pragma unroll
    for (int s = 0; s < 16; s += 4) {
        float4 v = *(const float4*)(A_log + d * 16 + s);
        Ac[s + 0] = -expf(v.x); Ac[s + 1] = -expf(v.y);
        Ac[s + 2] = -expf(v.z); Ac[s + 3] = -expf(v.w);
    }
    float a[16], h[16];
#pragma unroll
    for (int s = 0; s < 16; ++s) { a[s] = 1.f; h[s] = 0.f; }
    int base = b * 1024 + c * CL;
    for (int l = 0; l < CL; ++l) {
        int row = base + l;
        float dl = delta[row * 1024 + d];
        float xv = xic[row * 1024 + d];
        const float* bc = dbc + row * 64 + 32;
        float dxi = dl * xv;
#pragma unroll
        for (int s = 0; s < 16; s += 4) {
            float4 bV = *(const float4*)(bc + s);
            float dA0 = __expf(dl * Ac[s + 0]);
            float dA1 = __expf(dl * Ac[s + 1]);
            float dA2 = __expf(dl * Ac[s + 2]);
            float dA3 = __expf(dl * Ac[s + 3]);
            a[s + 0] *= dA0; h[s + 0] = dA0 * h[s + 0] + dxi * bV.x;
            a[s + 1] *= dA1; h[s + 1] = dA1 * h[s + 1] + dxi * bV.y;
            a[s + 2] *= dA2; h[s + 2] = dA2 * h[s + 2] + dxi * bV.z;
            a[s + 3] *= dA3; h[s + 3] = dA3 * h[s + 3] + dxi * bV.w;
        }
    }
    int off = ((b * NC + c) * 1024 + d) * 16;
#pragma unroll
    for (int s = 0; s < 16; s += 4) {
        *(float4*)(Pbuf + off + s) = make_float4(a[s], a[s + 1], a[s + 2], a[s + 3]);
        *(float4*)(Sbuf + off + s) = make_float4(h[s], h[s + 1], h[s + 2], h[s + 3]);
    }
}

// ---------------------------------------------------------------------------
// Carry combine across chunks (writes incoming states over Pbuf in place).
__global__ __launch_bounds__(NTHREADS) void scan_carry(
    float* __restrict__ Pbuf, const float* __restrict__ Sbuf)
{
    int b = blockIdx.x >> 2;
    int d = ((blockIdx.x & 3) << 8) + threadIdx.x;
    float H[16];
#pragma unroll
    for (int s = 0; s < 16; ++s) H[s] = 0.f;
    for (int c = 0; c < NC; ++c) {
        int off = ((b * NC + c) * 1024 + d) * 16;
        float P[16], S[16];
#pragma unroll
        for (int s = 0; s < 16; s += 4) {
            float4 pv = *(const float4*)(Pbuf + off + s);
            float4 sv = *(const float4*)(Sbuf + off + s);
            P[s] = pv.x; P[s + 1] = pv.y; P[s + 2] = pv.z; P[s + 3] = pv.w;
            S[s] = sv.x; S[s + 1] = sv.y; S[s + 2] = sv.z; S[s + 3] = sv.w;
        }
#pragma unroll
        for (int s = 0; s < 16; s += 4)
            *(float4*)(Pbuf + off + s) = make_float4(H[s], H[s + 1], H[s + 2], H[s + 3]);
#pragma unroll
        for (int s = 0; s < 16; ++s) H[s] = P[s] * H[s] + S[s];
    }
}

// ---------------------------------------------------------------------------
// Pass 2: re-run chunk from true incoming state; emit gated output as bf16.
__global__ __launch_bounds__(NTHREADS) void scan_p2(
    const float* __restrict__ delta, const float* __restrict__ xic,
    const float* __restrict__ dbc, const float* __restrict__ xz,
    const float* __restrict__ A_log, const float* __restrict__ Dp,
    const float* __restrict__ Hprev, unsigned short* __restrict__ yz)
{
    int blk = blockIdx.x;
    int g = blk & 3;
    int c = (blk >> 2) & (NC - 1);
    int b = blk >> 7;
    int d = (g << 8) + threadIdx.x;
    float Ac[16];
#pragma unroll
    for (int s = 0; s < 16; s += 4) {
        float4 v = *(const float4*)(A_log + d * 16 + s);
        Ac[s + 0] = -expf(v.x); Ac[s + 1] = -expf(v.y);
        Ac[s + 2] = -expf(v.z); Ac[s + 3] = -expf(v.w);
    }
    float dp = Dp[d];
    float h[16];
    int off = ((b * NC + c) * 1024 + d) * 16;
#pragma unroll
    for (int s = 0; s < 16; s += 4) {
        float4 hv = *(const float4*)(Hprev + off + s);
        h[s] = hv.x; h[s + 1] = hv.y; h[s + 2] = hv.z; h[s + 3] = hv.w;
    }
    int base = b * 1024 + c * CL;
    for (int l = 0; l < CL; ++l) {
        int row = base + l;
        float dl = delta[row * 1024 + d];
        float xv = xic[row * 1024 + d];
        float zv = xz[row * 2048 + 1024 + d];
        const float* bc = dbc + row * 64;
        float dxi = dl * xv;
        float y = 0.f;
#pragma unroll
        for (int s = 0; s < 16; s += 4) {
            float4 bV = *(const float4*)(bc + 32 + s);
            float4 cV = *(const float4*)(bc + 48 + s);
            float dA0 = __expf(dl * Ac[s + 0]);
            float dA1 = __expf(dl * Ac[s + 1]);
            float dA2 = __expf(dl * Ac[s + 2]);
            float dA3 = __expf(dl * Ac[s + 3]);
            h[s + 0] = dA0 * h[s + 0] + dxi * bV.x;
            h[s + 1] = dA1 * h[s + 1] + dxi * bV.y;
            h[s + 2] = dA2 * h[s + 2] + dxi * bV.z;
            h[s + 3] = dA3 * h[s + 3] + dxi * bV.w;
            y += h[s + 0] * cV.x + h[s + 1] * cV.y + h[s + 2] * cV.z + h[s + 3] * cV.w;
        }
        y += xv * dp;
        yz[row * 1024 + d] = f2bf(y * siluf(zv));
    }
}

// ---------------------------------------------------------------------------
__global__ __launch_bounds__(NTHREADS) void layernorm_ip(
    float* __restrict__ mo, const float* __restrict__ w, const float* __restrict__ bvec)
{
    int wv = threadIdx.x >> 6, lane = threadIdx.x & 63;
    int row = (blockIdx.x << 2) + wv;
    float* p = mo + row * 512;
    float4 v0 = ((const float4*)p)[lane];
    float4 v1 = ((const float4*)p)[lane + 64];
    float s = v0.x + v0.y + v0.z + v0.w + v1.x + v1.y + v1.z + v1.w;
    float q = v0.x * v0.x + v0.y * v0.y + v0.z * v0.z + v0.w * v0.w
            + v1.x * v1.x + v1.y * v1.y + v1.z * v1.z + v1.w * v1.w;
#pragma unroll
    for (int off = 32; off; off >>= 1) {
        s += __shfl_xor(s, off);
        q += __shfl_xor(q, off);
    }
    float mean = s * (1.f / 512.f);
    float var = q * (1.f / 512.f) - mean * mean;
    float rstd = rsqrtf(var + 1e-5f);
    float4 w0 = ((const float4*)w)[lane], w1 = ((const float4*)w)[lane + 64];
    float4 b0 = ((const float4*)bvec)[lane], b1 = ((const float4*)bvec)[lane + 64];
    v0.x = (v0.x - mean) * rstd * w0.x + b0.x;
    v0.y = (v0.y - mean) * rstd * w0.y + b0.y;
    v0.z = (v0.z - mean) * rstd * w0.z + b0.z;
    v0.w = (v0.w - mean) * rstd * w0.w + b0.w;
    v1.x = (v1.x - mean) * rstd * w1.x + b1.x;
    v1.y = (v1.y - mean) * rstd * w1.y + b1.y;
    v1.z = (v1.z - mean) * rstd * w1.z + b1.z;
    v1.w = (v1.w - mean) * rstd * w1.w + b1.w;
    ((float4*)p)[lane] = v0;
    ((float4*)p)[lane + 64] = v1;
}

// ---------------------------------------------------------------------------
__global__ __launch_bounds__(NTHREADS) void head_k(
    const float* __restrict__ mo, const float* __restrict__ Wc,
    const float* __restrict__ ifw, const float* __restrict__ ifb,
    float* __restrict__ logits, float* __restrict__ imp)
{
    int wv = threadIdx.x >> 6, lane = threadIdx.x & 63;
    int row = (blockIdx.x << 2) + wv;
    const float* p = mo + row * 512 + lane * 8;
    float4 x0 = *(const float4*)p;
    float4 x1 = *(const float4*)(p + 4);
    float part[11];
#pragma unroll
    for (int c = 0; c < 10; ++c) {
        const float* wr = Wc + c * 512 + lane * 8;
        float4 w0 = *(const float4*)wr, w1 = *(const float4*)(wr + 4);
        part[c] = x0.x * w0.x + x0.y * w0.y + x0.z * w0.z + x0.w * w0.w
                + x1.x * w1.x + x1.y * w1.y + x1.z * w1.z + x1.w * w1.w;
    }
    {
        const float* wr = ifw + lane * 8;
        float4 w0 = *(const float4*)wr, w1 = *(const float4*)(wr + 4);
        part[10] = x0.x * w0.x + x0.y * w0.y + x0.z * w0.z + x0.w * w0.w
                 + x1.x * w1.x + x1.y * w1.y + x1.z * w1.z + x1.w * w1.w;
    }
#pragma unroll
    for (int i = 0; i < 11; ++i)
#pragma unroll
        for (int off = 32; off; off >>= 1) part[i] += __shfl_xor(part[i], off);
    if (lane == 0) {
#pragma unroll
        for (int c = 0; c < 10; ++c) logits[row * 10 + c] = part[c];
        imp[row] = part[10] + ifb[0];
    }
}

// ---------------------------------------------------------------------------
__global__ __launch_bounds__(NTHREADS) void final_k(
    const float* __restrict__ logits, const float* __restrict__ imp,
    const float* __restrict__ mark, float* __restrict__ out)
{
    __shared__ float sred[4];
    int b = blockIdx.x, tid = threadIdx.x;
    int wv = tid >> 6, lane = tid & 63;
    float m = -1e30f;
    for (int l = tid; l < 1024; l += NTHREADS) m = fmaxf(m, imp[b * 1024 + l]);
#pragma unroll
    for (int off = 32; off; off >>= 1) m = fmaxf(m, __shfl_xor(m, off));
    if (lane == 0) sred[wv] = m;
    __syncthreads();
    m = fmaxf(fmaxf(sred[0], sred[1]), fmaxf(sred[2], sred[3]));
    __syncthreads();
    float den = 0.f, num[10];
#pragma unroll
    for (int c = 0; c < 10; ++c) num[c] = 0.f;
    for (int l = tid; l < 1024; l += NTHREADS) {
        float e = __expf(imp[b * 1024 + l] - m);
        float mk = mark[b * 1024 + l];
        den += e * mk;
        float w2 = e * mk * mk;
        const float* lg = logits + (b * 1024 + l) * 10;
#pragma unroll
        for (int c = 0; c < 10; ++c) num[c] += lg[c] * w2;
    }
#pragma unroll
    for (int off = 32; off; off >>= 1) den += __shfl_xor(den, off);
    if (lane == 0) sred[wv] = den;
    __syncthreads();
    den = sred[0] + sred[1] + sred[2] + sred[3];
    __syncthreads();
#pragma unroll
    for (int c = 0; c < 10; ++c) {
        float v = num[c];
#pragma unroll
        for (int off = 32; off; off >>= 1) v += __shfl_xor(v, off);
        if (lane == 0) sred[wv] = v;
        __syncthreads();
        v = sred[0] + sred[1] + sred[2] + sred[3];
        __syncthreads();
        num[c] = v;
    }
    if (tid == 0) {
        float inv = 1.f / den;
#pragma unroll
        for (int c = 0; c < 10; ++c) out[b * 10 + c] = num[c] * inv;
    }
}

// ---------------------------------------------------------------------------
extern "C" void kernel_launch(void* const* d_in, const int* in_sizes, int n_in,
                              void* d_out, int out_size, void* d_ws, size_t ws_size,
                              hipStream_t stream) {
    (void)in_sizes; (void)n_in; (void)out_size; (void)ws_size;
    const float* x_enc      = (const float*)d_in[0];
    const float* mark       = (const float*)d_in[1];
    const float* conv_w     = (const float*)d_in[4];
    const float* in_proj_w  = (const float*)d_in[5];
    const float* conv1d_w   = (const float*)d_in[6];
    const float* conv1d_b   = (const float*)d_in[7];
    const float* x_proj_w   = (const float*)d_in[8];
    const float* dt_proj_w  = (const float*)d_in[9];
    const float* dt_proj_b  = (const float*)d_in[10];
    const float* A_log      = (const float*)d_in[11];
    const float* Dp         = (const float*)d_in[12];
    const float* out_proj_w = (const float*)d_in[13];
    const float* ln_w       = (const float*)d_in[14];
    const float* ln_b       = (const float*)d_in[15];
    const float* out_layer_w= (const float*)d_in[16];
    const float* if_w       = (const float*)d_in[17];
    const float* if_b       = (const float*)d_in[18];
    float* out = (float*)d_out;

    // ---- workspace layout (bytes) ----
    char* ws = (char*)d_ws;
    float* Aemb    = (float*)(ws + 0);          // 1,572,864  (later: logits/imp)
    float* xbuf    = (float*)(ws + 1572864);    // 8,388,608  (later: mo)
    float* xz      = (float*)(ws + 9961472);    // 33,554,432
    float* xic     = (float*)(ws + 43515904);   // 16,777,216 (first 2MB first used as Wip_bf)
    float* dbc     = (float*)(ws + 60293120);   // 1,048,576
    float* delta   = (float*)(ws + 61341696);   // 16,777,216 (first 4MB: Abf, then xpart 8MB)
    float* scratch = (float*)(ws + 78118912);   // 16,777,216 (Xibf 8MB; then P|S; S later Ybf)
    unsigned short* Wxp_bf = (unsigned short*)(ws + 94896128);  // 131,072
    unsigned short* Wop_bf = (unsigned short*)(ws + 95027200);  // 1,048,576
    // aliases
    unsigned short* Abf   = (unsigned short*)delta;     // 4MB, dead after in_proj
    float* xpart          = delta;                      // 8MB split-K partials (after in_proj)
    unsigned short* Wip_bf= (unsigned short*)xic;       // 2MB, dead before dwconv writes xic
    unsigned short* Xibf  = (unsigned short*)scratch;   // 8MB, dead before scan_p1 writes P/S
    float* Pbuf   = scratch;                            // 8MB
    float* Sbuf   = scratch + 2097152;                  // 8MB
    float* Hprev  = Pbuf;                               // carry in place
    unsigned short* Ybf = (unsigned short*)Sbuf;        // 8MB, S dead after carry
    float* mo     = xbuf;
    float* logits = Aemb;
    float* impb   = Aemb + 4096 * 10;

    // 1. weight conversions (independent)
    cvt_bf16<<<1024, NTHREADS, 0, stream>>>(in_proj_w, Wip_bf, 262144);
    cvt_bf16<<<64,   NTHREADS, 0, stream>>>(x_proj_w,  Wxp_bf, 16384);
    cvt_bf16<<<512,  NTHREADS, 0, stream>>>(out_proj_w, Wop_bf, 131072);
    // 2. im2col gather + embed GEMM (fp32): (4096x96) @ (512x96)^T -> xbuf
    gather_embed<<<1536, NTHREADS, 0, stream>>>(x_enc, Aemb);
    gemm_nt<<<dim3(64, 8), NTHREADS, 0, stream>>>(Aemb, 96, conv_w, 96, nullptr, xbuf, 512, 96, 0);
    // 3. + positional embedding -> bf16 A
    posemb_bf<<<2048, NTHREADS, 0, stream>>>(xbuf, Abf);
    // 4. in_proj (MFMA): (4096x512) @ (2048x512)^T -> xz
    gemm_bf16_t<128,128,1><<<dim3(32, 16, 1), NTHREADS, 0, stream>>>(
        Abf, Wip_bf, xz, 2048, 512, 0);
    // 5. depthwise conv + SiLU -> xic (fp32) + Xibf (bf16)
    dwconv_silu<<<16384, NTHREADS, 0, stream>>>(xz, conv1d_w, conv1d_b, xic, Xibf);
    // 6. x_proj (MFMA, split-K=8): (4096x1024) @ (64x1024)^T -> xpart -> dbc
    gemm_bf16_t<128,64,8><<<dim3(32, 1, 8), NTHREADS, 0, stream>>>(
        Xibf, Wxp_bf, xpart, 64, 1024, 4096LL * 64);
    reduce_k8<<<256, NTHREADS, 0, stream>>>(xpart, dbc);
    // 7. dt_proj + bias + softplus (fp32): -> delta
    gemm_nt<<<dim3(64, 16), NTHREADS, 0, stream>>>(dbc, 64, dt_proj_w, 32, dt_proj_b, delta, 1024, 32, 1);
    // 8. chunked selective scan -> Ybf (bf16)
    scan_p1<<<512, NTHREADS, 0, stream>>>(delta, xic, dbc, A_log, Pbuf, Sbuf);
    scan_carry<<<16, NTHREADS, 0, stream>>>(Pbuf, Sbuf);
    scan_p2<<<512, NTHREADS, 0, stream>>>(delta, xic, dbc, xz, A_log, Dp, Hprev, Ybf);
    // 9. out_proj (MFMA): (4096x1024) @ (512x1024)^T -> mo
    gemm_bf16_t<128,64,1><<<dim3(32, 8, 1), NTHREADS, 0, stream>>>(
        Ybf, Wop_bf, mo, 512, 1024, 0);
    // 10-12. LayerNorm, heads, pooling
    layernorm_ip<<<1024, NTHREADS, 0, stream>>>(mo, ln_w, ln_b);
    head_k<<<1024, NTHREADS, 0, stream>>>(mo, out_layer_w, if_w, if_b, logits, impb);
    final_k<<<4, NTHREADS, 0, stream>>>(logits, impb, mark, out);
}

// Round 5
// 261.438 us; speedup vs baseline: 3.4360x; 1.0256x over previous
//
#include <hip/hip_runtime.h>
#include <math.h>

#define NTHREADS 256
#define NC 32   // scan chunks
#define CL 32   // chunk length (NC*CL = 1024)

typedef __attribute__((ext_vector_type(8))) short bf16x8;
typedef __attribute__((ext_vector_type(4))) float f32x4;

static __device__ __forceinline__ float siluf(float x) {
    return x / (1.f + __expf(-x));
}
static __device__ __forceinline__ float softplusf(float x) {
    return fmaxf(x, 0.f) + log1pf(__expf(-fabsf(x)));
}
static __device__ __forceinline__ unsigned short f2bf(float f) {
    unsigned int u = __float_as_uint(f);
    u = (u + 0x7fffu + ((u >> 16) & 1u)) >> 16;
    return (unsigned short)u;
}
static __device__ __forceinline__ float bf2f(unsigned short u) {
    return __uint_as_float((unsigned int)u << 16);
}

// ---------------------------------------------------------------------------
// fp32 -> bf16 bulk convert (n4 = count of float4 groups)
__global__ __launch_bounds__(NTHREADS) void cvt_bf16(
    const float* __restrict__ in, unsigned short* __restrict__ out, int n4)
{
    int i = blockIdx.x * NTHREADS + threadIdx.x;
    if (i >= n4) return;
    float4 v = *(const float4*)(in + i * 4);
    ushort4 o;
    o.x = f2bf(v.x); o.y = f2bf(v.y); o.z = f2bf(v.z); o.w = f2bf(v.w);
    *(ushort4*)(out + i * 4) = o;
}

// ---------------------------------------------------------------------------
// Gather the im2col matrix for the embedding conv (edge-padded, k=3).
__global__ __launch_bounds__(NTHREADS) void gather_embed(
    const float* __restrict__ xe, float* __restrict__ Aemb)
{
    int idx = blockIdx.x * NTHREADS + threadIdx.x; // 4096*96
    int row = idx / 96, k = idx % 96;
    int c = k / 3, j = k % 3;
    int b = row >> 10, t = row & 1023;
    int tc = min(max(t + j - 2, 0), 1023);
    Aemb[idx] = xe[(b * 1024 + tc) * 32 + c];
}

// ---------------------------------------------------------------------------
// Generic fp32 GEMM: C[M,N] = A[M,K] @ B[N,K]^T
// act 0: plain f32 out; act 1: +bias, softplus, f32 out;
// act 2: + sinusoidal positional embedding, bf16 out to Cbf (embed fusion).
__global__ __launch_bounds__(NTHREADS) void gemm_nt(
    const float* __restrict__ A, int lda,
    const float* __restrict__ B, int ldb,
    const float* __restrict__ bias,
    float* __restrict__ C, unsigned short* __restrict__ Cbf, int ldc,
    int K, int act)
{
    __shared__ float As[16][68];
    __shared__ float Bs[16][68];
    const int tid = threadIdx.x;
    const int tx = tid & 15, ty = tid >> 4;
    const int m0 = blockIdx.x * 64, n0 = blockIdx.y * 64;
    const int lr = tid >> 2;
    const int lc = (tid & 3) << 2;
    float acc[4][4] = {{0.f}};
    const float* Ap = A + (m0 + lr) * lda + lc;
    const float* Bp = B + (n0 + lr) * ldb + lc;
    for (int k0 = 0; k0 < K; k0 += 16) {
        float4 av = *(const float4*)(Ap + k0);
        float4 bv = *(const float4*)(Bp + k0);
        __syncthreads();
        As[lc + 0][lr] = av.x; As[lc + 1][lr] = av.y;
        As[lc + 2][lr] = av.z; As[lc + 3][lr] = av.w;
        Bs[lc + 0][lr] = bv.x; Bs[lc + 1][lr] = bv.y;
        Bs[lc + 2][lr] = bv.z; Bs[lc + 3][lr] = bv.w;
        __syncthreads();
#pragma unroll
        for (int kk = 0; kk < 16; ++kk) {
            float4 a = *(const float4*)&As[kk][ty << 2];
            float4 b = *(const float4*)&Bs[kk][tx << 2];
            acc[0][0] += a.x * b.x; acc[0][1] += a.x * b.y;
            acc[0][2] += a.x * b.z; acc[0][3] += a.x * b.w;
            acc[1][0] += a.y * b.x; acc[1][1] += a.y * b.y;
            acc[1][2] += a.y * b.z; acc[1][3] += a.y * b.w;
            acc[2][0] += a.z * b.x; acc[2][1] += a.z * b.y;
            acc[2][2] += a.z * b.z; acc[2][3] += a.z * b.w;
            acc[3][0] += a.w * b.x; acc[3][1] += a.w * b.y;
            acc[3][2] += a.w * b.z; acc[3][3] += a.w * b.w;
        }
    }
    const float lf = 9.210340372f / 512.f;   // ln(10000)/512
#pragma unroll
    for (int i = 0; i < 4; ++i) {
        int mrow = m0 + (ty << 2) + i;
#pragma unroll
        for (int j = 0; j < 4; ++j) {
            int ncol = n0 + (tx << 2) + j;
            float v = acc[i][j];
            if (act == 1) v = softplusf(v + bias[ncol]);
            if (act == 2) {
                int t = mrow & 1023;
                float freq = __expf(-(float)(ncol & ~1) * lf);
                float ang = (float)t * freq;
                v += (ncol & 1) ? cosf(ang) : sinf(ang);
                Cbf[(size_t)mrow * ldc + ncol] = f2bf(v);
            } else {
                C[(size_t)mrow * ldc + ncol] = v;
            }
        }
    }
}

// ---------------------------------------------------------------------------
// bf16 MFMA GEMM (templated): C[M,N] = A[M,K](bf16) @ B[N,K](bf16)^T
// Swapped-operand MFMA (lane holds 4 consecutive C cols). Epilogue stages the
// tile in LDS (64-row halves) and stores with fully linear 4KB-per-instruction
// writes (16 rows x 256B contiguous) to avoid partial-line write amplification.
// OUTBF: emit bf16 output; else f32. KSPLIT>1: partials at blockIdx.z*partStride.
template<int BM, int BN, int KSPLIT, bool OUTBF>
__global__ __launch_bounds__(NTHREADS) void gemm_bf16_t(
    const unsigned short* __restrict__ A,
    const unsigned short* __restrict__ B,
    void* __restrict__ Cvoid, int N, int K, long long partStride)
{
    constexpr int WRN = (BN == 128) ? 2 : 1;   // waves along N
    constexpr int WRM = 4 / WRN;               // waves along M
    constexpr int WTM = BM / WRM;              // wave tile M
    constexpr int WTN = BN / WRN;              // wave tile N (64)
    constexpr int FI = WTM / 16;
    constexpr int FJ = WTN / 16;
    constexpr int PA = BM / 32;
    constexpr int PB = BN / 32;
    constexpr int EB = OUTBF ? 2 : 4;          // output element bytes
    constexpr int PITCH = (BN + 8) * EB;       // staged row pitch (padded)
    constexpr int ROWB = BN * EB;              // staged row payload bytes
    constexpr int MAIN = (BM + BN) * 128;
    constexpr int STAGE = 64 * PITCH;
    constexpr int LDSB = MAIN > STAGE ? MAIN : STAGE;

    __shared__ __align__(16) char lds[LDSB];
    char* Ab = lds;
    char* Bb = lds + BM * 128;

    const int tid = threadIdx.x;
    const int lane = tid & 63;
    const int w = tid >> 6;
    const int wr = w / WRN, wc = w % WRN;
    const int m0 = blockIdx.x * BM, n0 = blockIdx.y * BN;
    const int kper = K / KSPLIT;
    const int kbeg = blockIdx.z * kper;

    const int rt = tid >> 3;
    const int c16 = tid & 7;
    const int wbyte = (c16 * 16) ^ ((rt & 7) << 4);

    f32x4 acc[FI][FJ] = {};

    const unsigned short* Ap = A + (size_t)(m0 + rt) * K + kbeg + c16 * 8;
    const unsigned short* Bp = B + (size_t)(n0 + rt) * K + kbeg + c16 * 8;

    uint4 ra[PA], rb[PB];
#pragma unroll
    for (int p = 0; p < PA; ++p) ra[p] = *(const uint4*)(Ap + (size_t)p * 32 * K);
#pragma unroll
    for (int p = 0; p < PB; ++p) rb[p] = *(const uint4*)(Bp + (size_t)p * 32 * K);

    for (int k0 = 0; k0 < kper; k0 += 64) {
        __syncthreads();
#pragma unroll
        for (int p = 0; p < PA; ++p) *(uint4*)(Ab + (rt + p * 32) * 128 + wbyte) = ra[p];
#pragma unroll
        for (int p = 0; p < PB; ++p) *(uint4*)(Bb + (rt + p * 32) * 128 + wbyte) = rb[p];
        __syncthreads();
        if (k0 + 64 < kper) {
#pragma unroll
            for (int p = 0; p < PA; ++p) ra[p] = *(const uint4*)(Ap + (size_t)p * 32 * K + k0 + 64);
#pragma unroll
            for (int p = 0; p < PB; ++p) rb[p] = *(const uint4*)(Bp + (size_t)p * 32 * K + k0 + 64);
        }
#pragma unroll
        for (int kk = 0; kk < 2; ++kk) {
            const int kb = kk * 64 + ((lane >> 4) << 4);
            const int rxor = (lane & 7) << 4;
            bf16x8 af[FI], bfr[FJ];
#pragma unroll
            for (int i = 0; i < FI; ++i) {
                int arow = wr * WTM + i * 16 + (lane & 15);
                af[i] = *(const bf16x8*)(Ab + arow * 128 + (kb ^ rxor));
            }
#pragma unroll
            for (int j = 0; j < FJ; ++j) {
                int brow = wc * WTN + j * 16 + (lane & 15);
                bfr[j] = *(const bf16x8*)(Bb + brow * 128 + (kb ^ rxor));
            }
#pragma unroll
            for (int i = 0; i < FI; ++i)
#pragma unroll
                for (int j = 0; j < FJ; ++j)
                    acc[i][j] = __builtin_amdgcn_mfma_f32_16x16x32_bf16(
                        bfr[j], af[i], acc[i][j], 0, 0, 0);   // swapped -> lane holds C cols
        }
    }

    // ---- LDS-staged epilogue: linear full-line stores ----
    __syncthreads();   // all LDS reads of the K-loop done
    constexpr int NQ = 64 * ROWB / (NTHREADS * 16);
#pragma unroll
    for (int h = 0; h < BM / 64; ++h) {
        if ((wr * WTM) / 64 == h) {
#pragma unroll
            for (int i = 0; i < FI; ++i) {
                int lr = wr * WTM - h * 64 + i * 16 + (lane & 15);
#pragma unroll
                for (int j = 0; j < FJ; ++j) {
                    int col = wc * WTN + j * 16 + ((lane >> 4) << 2);
                    if (OUTBF) {
                        ushort4 o;
                        o.x = f2bf(acc[i][j][0]); o.y = f2bf(acc[i][j][1]);
                        o.z = f2bf(acc[i][j][2]); o.w = f2bf(acc[i][j][3]);
                        *(ushort4*)(lds + lr * PITCH + col * 2) = o;
                    } else {
                        *(f32x4*)(lds + lr * PITCH + col * 4) = acc[i][j];
                    }
                }
            }
        }
        __syncthreads();
#pragma unroll
        for (int q = 0; q < NQ; ++q) {
            int idx = q * NTHREADS + tid;
            int row = idx * 16 / ROWB;
            int colB = (idx * 16) % ROWB;
            uint4 v = *(const uint4*)(lds + row * PITCH + colB);
            char* Cg = (char*)Cvoid + (long long)blockIdx.z * partStride * EB;
            *(uint4*)(Cg + (size_t)(m0 + h * 64 + row) * ((size_t)N * EB)
                         + (size_t)n0 * EB + colB) = v;
        }
        __syncthreads();
    }
}

// ---------------------------------------------------------------------------
// Reduce split-K partials: out[i] = sum_z part[z*stride + i]  (float4 lanes)
__global__ __launch_bounds__(NTHREADS) void reduce_k8(
    const float* __restrict__ part, float* __restrict__ out)
{
    int i = blockIdx.x * NTHREADS + threadIdx.x;   // 65536 float4 groups
    const size_t stride = 4096 * 64;
    float4 s = *(const float4*)(part + (size_t)i * 4);
#pragma unroll
    for (int z = 1; z < 8; ++z) {
        float4 v = *(const float4*)(part + z * stride + (size_t)i * 4);
        s.x += v.x; s.y += v.y; s.z += v.z; s.w += v.w;
    }
    *(float4*)(out + (size_t)i * 4) = s;
}

// ---------------------------------------------------------------------------
// Depthwise causal conv1d + bias + SiLU. xz is bf16 now.
__global__ __launch_bounds__(NTHREADS) void dwconv_silu(
    const unsigned short* __restrict__ xz, const float* __restrict__ w,
    const float* __restrict__ bias, float* __restrict__ out,
    unsigned short* __restrict__ outbf)
{
    int idx = blockIdx.x * NTHREADS + threadIdx.x; // 4096*1024
    int row = idx >> 10;
    int d = idx & 1023;
    int b = row >> 10, l = row & 1023;
    float acc = bias[d];
#pragma unroll
    for (int j = 0; j < 4; ++j) {
        int ls = l - 3 + j;
        if (ls >= 0) acc += bf2f(xz[(size_t)(b * 1024 + ls) * 2048 + d]) * w[d * 4 + j];
    }
    float s = siluf(acc);
    out[idx] = s;
    outbf[idx] = f2bf(s);
}

// ---------------------------------------------------------------------------
// Chunked selective scan, pass 1.
__global__ __launch_bounds__(NTHREADS) void scan_p1(
    const float* __restrict__ delta, const float* __restrict__ xic,
    const float* __restrict__ dbc, const float* __restrict__ A_log,
    float* __restrict__ Pbuf, float* __restrict__ Sbuf)
{
    int blk = blockIdx.x;              // ((b*NC + c)*4 + g)
    int g = blk & 3;
    int c = (blk >> 2) & (NC - 1);
    int b = blk >> 7;
    int d = (g << 8) + threadIdx.x;
    float Ac[16];
#pragma unroll
    for (int s = 0; s < 16; s += 4) {
        float4 v = *(const float4*)(A_log + d * 16 + s);
        Ac[s + 0] = -expf(v.x); Ac[s + 1] = -expf(v.y);
        Ac[s + 2] = -expf(v.z); Ac[s + 3] = -expf(v.w);
    }
    float a[16], h[16];
#pragma unroll
    for (int s = 0; s < 16; ++s) { a[s] = 1.f; h[s] = 0.f; }
    int base = b * 1024 + c * CL;
    for (int l = 0; l < CL; ++l) {
        int row = base + l;
        float dl = delta[row * 1024 + d];
        float xv = xic[row * 1024 + d];
        const float* bc = dbc + row * 64 + 32;
        float dxi = dl * xv;
#pragma unroll
        for (int s = 0; s < 16; s += 4) {
            float4 bV = *(const float4*)(bc + s);
            float dA0 = __expf(dl * Ac[s + 0]);
            float dA1 = __expf(dl * Ac[s + 1]);
            float dA2 = __expf(dl * Ac[s + 2]);
            float dA3 = __expf(dl * Ac[s + 3]);
            a[s + 0] *= dA0; h[s + 0] = dA0 * h[s + 0] + dxi * bV.x;
            a[s + 1] *= dA1; h[s + 1] = dA1 * h[s + 1] + dxi * bV.y;
            a[s + 2] *= dA2; h[s + 2] = dA2 * h[s + 2] + dxi * bV.z;
            a[s + 3] *= dA3; h[s + 3] = dA3 * h[s + 3] + dxi * bV.w;
        }
    }
    int off = ((b * NC + c) * 1024 + d) * 16;
#pragma unroll
    for (int s = 0; s < 16; s += 4) {
        *(float4*)(Pbuf + off + s) = make_float4(a[s], a[s + 1], a[s + 2], a[s + 3]);
        *(float4*)(Sbuf + off + s) = make_float4(h[s], h[s + 1], h[s + 2], h[s + 3]);
    }
}

// ---------------------------------------------------------------------------
// Carry combine across chunks (writes incoming states over Pbuf in place).
__global__ __launch_bounds__(NTHREADS) void scan_carry(
    float* __restrict__ Pbuf, const float* __restrict__ Sbuf)
{
    int b = blockIdx.x >> 2;
    int d = ((blockIdx.x & 3) << 8) + threadIdx.x;
    float H[16];
#pragma unroll
    for (int s = 0; s < 16; ++s) H[s] = 0.f;
    for (int c = 0; c < NC; ++c) {
        int off = ((b * NC + c) * 1024 + d) * 16;
        float P[16], S[16];
#pragma unroll
        for (int s = 0; s < 16; s += 4) {
            float4 pv = *(const float4*)(Pbuf + off + s);
            float4 sv = *(const float4*)(Sbuf + off + s);
            P[s] = pv.x; P[s + 1] = pv.y; P[s + 2] = pv.z; P[s + 3] = pv.w;
            S[s] = sv.x; S[s + 1] = sv.y; S[s + 2] = sv.z; S[s + 3] = sv.w;
        }
#pragma unroll
        for (int s = 0; s < 16; s += 4)
            *(float4*)(Pbuf + off + s) = make_float4(H[s], H[s + 1], H[s + 2], H[s + 3]);
#pragma unroll
        for (int s = 0; s < 16; ++s) H[s] = P[s] * H[s] + S[s];
    }
}

// ---------------------------------------------------------------------------
// Pass 2: re-run chunk from true incoming state; emit gated output as bf16.
__global__ __launch_bounds__(NTHREADS) void scan_p2(
    const float* __restrict__ delta, const float* __restrict__ xic,
    const float* __restrict__ dbc, const unsigned short* __restrict__ xz,
    const float* __restrict__ A_log, const float* __restrict__ Dp,
    const float* __restrict__ Hprev, unsigned short* __restrict__ yz)
{
    int blk = blockIdx.x;
    int g = blk & 3;
    int c = (blk >> 2) & (NC - 1);
    int b = blk >> 7;
    int d = (g << 8) + threadIdx.x;
    float Ac[16];
#pragma unroll
    for (int s = 0; s < 16; s += 4) {
        float4 v = *(const float4*)(A_log + d * 16 + s);
        Ac[s + 0] = -expf(v.x); Ac[s + 1] = -expf(v.y);
        Ac[s + 2] = -expf(v.z); Ac[s + 3] = -expf(v.w);
    }
    float dp = Dp[d];
    float h[16];
    int off = ((b * NC + c) * 1024 + d) * 16;
#pragma unroll
    for (int s = 0; s < 16; s += 4) {
        float4 hv = *(const float4*)(Hprev + off + s);
        h[s] = hv.x; h[s + 1] = hv.y; h[s + 2] = hv.z; h[s + 3] = hv.w;
    }
    int base = b * 1024 + c * CL;
    for (int l = 0; l < CL; ++l) {
        int row = base + l;
        float dl = delta[row * 1024 + d];
        float xv = xic[row * 1024 + d];
        float zv = bf2f(xz[(size_t)row * 2048 + 1024 + d]);
        const float* bc = dbc + row * 64;
        float dxi = dl * xv;
        float y = 0.f;
#pragma unroll
        for (int s = 0; s < 16; s += 4) {
            float4 bV = *(const float4*)(bc + 32 + s);
            float4 cV = *(const float4*)(bc + 48 + s);
            float dA0 = __expf(dl * Ac[s + 0]);
            float dA1 = __expf(dl * Ac[s + 1]);
            float dA2 = __expf(dl * Ac[s + 2]);
            float dA3 = __expf(dl * Ac[s + 3]);
            h[s + 0] = dA0 * h[s + 0] + dxi * bV.x;
            h[s + 1] = dA1 * h[s + 1] + dxi * bV.y;
            h[s + 2] = dA2 * h[s + 2] + dxi * bV.z;
            h[s + 3] = dA3 * h[s + 3] + dxi * bV.w;
            y += h[s + 0] * cV.x + h[s + 1] * cV.y + h[s + 2] * cV.z + h[s + 3] * cV.w;
        }
        y += xv * dp;
        yz[row * 1024 + d] = f2bf(y * siluf(zv));
    }
}

// ---------------------------------------------------------------------------
__global__ __launch_bounds__(NTHREADS) void layernorm_ip(
    float* __restrict__ mo, const float* __restrict__ w, const float* __restrict__ bvec)
{
    int wv = threadIdx.x >> 6, lane = threadIdx.x & 63;
    int row = (blockIdx.x << 2) + wv;
    float* p = mo + row * 512;
    float4 v0 = ((const float4*)p)[lane];
    float4 v1 = ((const float4*)p)[lane + 64];
    float s = v0.x + v0.y + v0.z + v0.w + v1.x + v1.y + v1.z + v1.w;
    float q = v0.x * v0.x + v0.y * v0.y + v0.z * v0.z + v0.w * v0.w
            + v1.x * v1.x + v1.y * v1.y + v1.z * v1.z + v1.w * v1.w;
#pragma unroll
    for (int off = 32; off; off >>= 1) {
        s += __shfl_xor(s, off);
        q += __shfl_xor(q, off);
    }
    float mean = s * (1.f / 512.f);
    float var = q * (1.f / 512.f) - mean * mean;
    float rstd = rsqrtf(var + 1e-5f);
    float4 w0 = ((const float4*)w)[lane], w1 = ((const float4*)w)[lane + 64];
    float4 b0 = ((const float4*)bvec)[lane], b1 = ((const float4*)bvec)[lane + 64];
    v0.x = (v0.x - mean) * rstd * w0.x + b0.x;
    v0.y = (v0.y - mean) * rstd * w0.y + b0.y;
    v0.z = (v0.z - mean) * rstd * w0.z + b0.z;
    v0.w = (v0.w - mean) * rstd * w0.w + b0.w;
    v1.x = (v1.x - mean) * rstd * w1.x + b1.x;
    v1.y = (v1.y - mean) * rstd * w1.y + b1.y;
    v1.z = (v1.z - mean) * rstd * w1.z + b1.z;
    v1.w = (v1.w - mean) * rstd * w1.w + b1.w;
    ((float4*)p)[lane] = v0;
    ((float4*)p)[lane + 64] = v1;
}

// ---------------------------------------------------------------------------
__global__ __launch_bounds__(NTHREADS) void head_k(
    const float* __restrict__ mo, const float* __restrict__ Wc,
    const float* __restrict__ ifw, const float* __restrict__ ifb,
    float* __restrict__ logits, float* __restrict__ imp)
{
    int wv = threadIdx.x >> 6, lane = threadIdx.x & 63;
    int row = (blockIdx.x << 2) + wv;
    const float* p = mo + row * 512 + lane * 8;
    float4 x0 = *(const float4*)p;
    float4 x1 = *(const float4*)(p + 4);
    float part[11];
#pragma unroll
    for (int c = 0; c < 10; ++c) {
        const float* wr = Wc + c * 512 + lane * 8;
        float4 w0 = *(const float4*)wr, w1 = *(const float4*)(wr + 4);
        part[c] = x0.x * w0.x + x0.y * w0.y + x0.z * w0.z + x0.w * w0.w
                + x1.x * w1.x + x1.y * w1.y + x1.z * w1.z + x1.w * w1.w;
    }
    {
        const float* wr = ifw + lane * 8;
        float4 w0 = *(const float4*)wr, w1 = *(const float4*)(wr + 4);
        part[10] = x0.x * w0.x + x0.y * w0.y + x0.z * w0.z + x0.w * w0.w
                 + x1.x * w1.x + x1.y * w1.y + x1.z * w1.z + x1.w * w1.w;
    }
#pragma unroll
    for (int i = 0; i < 11; ++i)
#pragma unroll
        for (int off = 32; off; off >>= 1) part[i] += __shfl_xor(part[i], off);
    if (lane == 0) {
#pragma unroll
        for (int c = 0; c < 10; ++c) logits[row * 10 + c] = part[c];
        imp[row] = part[10] + ifb[0];
    }
}

// ---------------------------------------------------------------------------
__global__ __launch_bounds__(NTHREADS) void final_k(
    const float* __restrict__ logits, const float* __restrict__ imp,
    const float* __restrict__ mark, float* __restrict__ out)
{
    __shared__ float sred[4];
    int b = blockIdx.x, tid = threadIdx.x;
    int wv = tid >> 6, lane = tid & 63;
    float m = -1e30f;
    for (int l = tid; l < 1024; l += NTHREADS) m = fmaxf(m, imp[b * 1024 + l]);
#pragma unroll
    for (int off = 32; off; off >>= 1) m = fmaxf(m, __shfl_xor(m, off));
    if (lane == 0) sred[wv] = m;
    __syncthreads();
    m = fmaxf(fmaxf(sred[0], sred[1]), fmaxf(sred[2], sred[3]));
    __syncthreads();
    float den = 0.f, num[10];
#pragma unroll
    for (int c = 0; c < 10; ++c) num[c] = 0.f;
    for (int l = tid; l < 1024; l += NTHREADS) {
        float e = __expf(imp[b * 1024 + l] - m);
        float mk = mark[b * 1024 + l];
        den += e * mk;
        float w2 = e * mk * mk;
        const float* lg = logits + (b * 1024 + l) * 10;
#pragma unroll
        for (int c = 0; c < 10; ++c) num[c] += lg[c] * w2;
    }
#pragma unroll
    for (int off = 32; off; off >>= 1) den += __shfl_xor(den, off);
    if (lane == 0) sred[wv] = den;
    __syncthreads();
    den = sred[0] + sred[1] + sred[2] + sred[3];
    __syncthreads();
#pragma unroll
    for (int c = 0; c < 10; ++c) {
        float v = num[c];
#pragma unroll
        for (int off = 32; off; off >>= 1) v += __shfl_xor(v, off);
        if (lane == 0) sred[wv] = v;
        __syncthreads();
        v = sred[0] + sred[1] + sred[2] + sred[3];
        __syncthreads();
        num[c] = v;
    }
    if (tid == 0) {
        float inv = 1.f / den;
#pragma unroll
        for (int c = 0; c < 10; ++c) out[b * 10 + c] = num[c] * inv;
    }
}

// ---------------------------------------------------------------------------
extern "C" void kernel_launch(void* const* d_in, const int* in_sizes, int n_in,
                              void* d_out, int out_size, void* d_ws, size_t ws_size,
                              hipStream_t stream) {
    (void)in_sizes; (void)n_in; (void)out_size; (void)ws_size;
    const float* x_enc      = (const float*)d_in[0];
    const float* mark       = (const float*)d_in[1];
    const float* conv_w     = (const float*)d_in[4];
    const float* in_proj_w  = (const float*)d_in[5];
    const float* conv1d_w   = (const float*)d_in[6];
    const float* conv1d_b   = (const float*)d_in[7];
    const float* x_proj_w   = (const float*)d_in[8];
    const float* dt_proj_w  = (const float*)d_in[9];
    const float* dt_proj_b  = (const float*)d_in[10];
    const float* A_log      = (const float*)d_in[11];
    const float* Dp         = (const float*)d_in[12];
    const float* out_proj_w = (const float*)d_in[13];
    const float* ln_w       = (const float*)d_in[14];
    const float* ln_b       = (const float*)d_in[15];
    const float* out_layer_w= (const float*)d_in[16];
    const float* if_w       = (const float*)d_in[17];
    const float* if_b       = (const float*)d_in[18];
    float* out = (float*)d_out;

    // ---- workspace layout (bytes) ----
    char* ws = (char*)d_ws;
    float* Aemb            = (float*)(ws + 0);          // 1,572,864 (later: logits/imp)
    float* mo              = (float*)(ws + 1572864);    // 8,388,608
    unsigned short* xzbf   = (unsigned short*)(ws + 9961472);   // 16,777,216 (4096x2048 bf16)
    float* xic             = (float*)(ws + 26738688);   // 16,777,216
    unsigned short* Xibf   = (unsigned short*)(ws + 43515904);  // 8,388,608
    float* dbc             = (float*)(ws + 51904512);   // 1,048,576
    float* delta           = (float*)(ws + 52953088);   // 16,777,216 (Abf 4MB, xpart 8MB aliases)
    float* scratch         = (float*)(ws + 69730304);   // 16,777,216 (Pbuf 8MB | Sbuf 8MB)
    unsigned short* Wip_bf = (unsigned short*)(ws + 86507520);  // 2,097,152
    unsigned short* Wxp_bf = (unsigned short*)(ws + 88604672);  // 131,072
    unsigned short* Wop_bf = (unsigned short*)(ws + 88735744);  // 1,048,576
    // aliases (sequentially dead)
    unsigned short* Abf = (unsigned short*)delta;  // 4MB, dead after in_proj
    float* xpart        = delta;                   // 8MB, dead after reduce_k8 (before delta write)
    float* Pbuf   = scratch;
    float* Sbuf   = scratch + 2097152;
    float* Hprev  = Pbuf;
    unsigned short* Ybf = (unsigned short*)Sbuf;   // S dead after carry
    float* logits = Aemb;
    float* impb   = Aemb + 4096 * 10;

    // 1. weight conversions
    cvt_bf16<<<1024, NTHREADS, 0, stream>>>(in_proj_w, Wip_bf, 262144);
    cvt_bf16<<<64,   NTHREADS, 0, stream>>>(x_proj_w,  Wxp_bf, 16384);
    cvt_bf16<<<512,  NTHREADS, 0, stream>>>(out_proj_w, Wop_bf, 131072);
    // 2. im2col gather + embed GEMM fused with posemb, bf16 out -> Abf
    gather_embed<<<1536, NTHREADS, 0, stream>>>(x_enc, Aemb);
    gemm_nt<<<dim3(64, 8), NTHREADS, 0, stream>>>(
        Aemb, 96, conv_w, 96, nullptr, nullptr, Abf, 512, 96, 2);
    // 3. in_proj (MFMA, bf16 out): (4096x512) @ (2048x512)^T -> xzbf
    gemm_bf16_t<128,128,1,true><<<dim3(32, 16, 1), NTHREADS, 0, stream>>>(
        Abf, Wip_bf, xzbf, 2048, 512, 0);
    // 4. depthwise conv + SiLU -> xic (f32) + Xibf (bf16)
    dwconv_silu<<<16384, NTHREADS, 0, stream>>>(xzbf, conv1d_w, conv1d_b, xic, Xibf);
    // 5. x_proj (MFMA, split-K=8): (4096x1024) @ (64x1024)^T -> xpart -> dbc
    gemm_bf16_t<128,64,8,false><<<dim3(32, 1, 8), NTHREADS, 0, stream>>>(
        Xibf, Wxp_bf, xpart, 64, 1024, 4096LL * 64);
    reduce_k8<<<256, NTHREADS, 0, stream>>>(xpart, dbc);
    // 6. dt_proj + bias + softplus (fp32) -> delta
    gemm_nt<<<dim3(64, 16), NTHREADS, 0, stream>>>(
        dbc, 64, dt_proj_w, 32, dt_proj_b, delta, nullptr, 1024, 32, 1);
    // 7. chunked selective scan -> Ybf (bf16)
    scan_p1<<<512, NTHREADS, 0, stream>>>(delta, xic, dbc, A_log, Pbuf, Sbuf);
    scan_carry<<<16, NTHREADS, 0, stream>>>(Pbuf, Sbuf);
    scan_p2<<<512, NTHREADS, 0, stream>>>(delta, xic, dbc, xzbf, A_log, Dp, Hprev, Ybf);
    // 8. out_proj (MFMA): (4096x1024) @ (512x1024)^T -> mo
    gemm_bf16_t<128,64,1,false><<<dim3(32, 8, 1), NTHREADS, 0, stream>>>(
        Ybf, Wop_bf, mo, 512, 1024, 0);
    // 9-11. LayerNorm, heads, pooling
    layernorm_ip<<<1024, NTHREADS, 0, stream>>>(mo, ln_w, ln_b);
    head_k<<<1024, NTHREADS, 0, stream>>>(mo, out_layer_w, if_w, if_b, logits, impb);
    final_k<<<4, NTHREADS, 0, stream>>>(logits, impb, mark, out);
}